// Round 9
// baseline (1070.612 us; speedup 1.0000x reference)
//
#include <hip/hip_runtime.h>
#include <hip/hip_bf16.h>

// EdgeAwareCritic: 3x GATv2 (H=2 heads, HID=128) + FiLM + MLP head, scalar output.
// fp32 inputs; GEMMs in bf16 MFMA. GAT = ONE edge-parallel kernel per layer:
// MFMA em-logits + exp (no max-sub; clamp 60) + segmented-scan + atomic
// accumulation of num[d,256]/den[d,2]; tiny per-node epilogue normalizes.

typedef __attribute__((ext_vector_type(8))) short bf16x8;   // 8 bf16 = 4 VGPR
typedef __attribute__((ext_vector_type(4))) float f32x4;

__device__ __forceinline__ unsigned short f2bf(float f) {
    union { float f; unsigned int i; } v; v.f = f;
    unsigned int x = v.i;
    x += 0x7fffu + ((x >> 16) & 1u);   // round-to-nearest-even
    return (unsigned short)(x >> 16);
}
__device__ __forceinline__ float4 b4f(ushort4 u) {
    union { unsigned int i; float f; } a, b, c, d;
    a.i = (unsigned int)u.x << 16; b.i = (unsigned int)u.y << 16;
    c.i = (unsigned int)u.z << 16; d.i = (unsigned int)u.w << 16;
    return make_float4(a.f, b.f, c.f, d.f);
}

// ---------------- multi-tensor fp32 -> bf16 convert (RNE) ----------------
#define MAXCVT 12
struct CvtDescs {
    const float* src[MAXCVT];
    unsigned short* dst[MAXCVT];
    int n4[MAXCVT];
    int cnt;
};
__global__ __launch_bounds__(256) void cvt_many_kernel(CvtDescs d) {
    const int tid = blockIdx.x * blockDim.x + threadIdx.x;
    const int stride = gridDim.x * blockDim.x;
    for (int e = 0; e < d.cnt; ++e) {
        const float4* s = (const float4*)d.src[e];
        ushort4* o = (ushort4*)d.dst[e];
        const int n = d.n4[e];
        for (int i = tid; i < n; i += stride) {
            float4 v = s[i];
            o[i] = make_ushort4(f2bf(v.x), f2bf(v.y), f2bf(v.z), f2bf(v.w));
        }
    }
}

// ---- row-pad convert: [rows,16] f32 -> [rows,32] bf16 (cols 16..31 = 0) ----
struct PadDescs {
    const float* src[4];
    unsigned short* dst[4];
    int rows[4];
    int cnt;
};
__global__ __launch_bounds__(256) void cvt_pad_kernel(PadDescs d) {
    const int tid = blockIdx.x * blockDim.x + threadIdx.x;
    const int stride = gridDim.x * blockDim.x;
    const ushort4 z = make_ushort4(0, 0, 0, 0);
    for (int e = 0; e < d.cnt; ++e) {
        const float4* s = (const float4*)d.src[e];
        ushort4* o = (ushort4*)d.dst[e];
        const int rows = d.rows[e];
        for (int r = tid; r < rows; r += stride) {
            const float4* sp = s + (size_t)r * 4;
            ushort4* op = o + (size_t)r * 8;
#pragma unroll
            for (int q = 0; q < 4; ++q) {
                float4 v = sp[q];
                op[q] = make_ushort4(f2bf(v.x), f2bf(v.y), f2bf(v.z), f2bf(v.w));
            }
#pragma unroll
            for (int q = 4; q < 8; ++q) op[q] = z;
        }
    }
}

// ---------------- CSR build ----------------
__global__ void hist_kernel(const int* __restrict__ dst, int* __restrict__ deg, int n) {
    int i = blockIdx.x * blockDim.x + threadIdx.x;
    if (i < n) atomicAdd(&deg[dst[i]], 1);
}

__global__ __launch_bounds__(1024) void scan_kernel(const int* __restrict__ deg,
                                                    int* __restrict__ rowp,
                                                    int* __restrict__ cur, int n) {
    __shared__ int sums[1024];
    const int t = threadIdx.x;
    const int PER = 20;
    int base = t * PER;
    int local[PER];
    int run = 0;
#pragma unroll
    for (int i = 0; i < PER; ++i) {
        int v = (base + i < n) ? deg[base + i] : 0;
        local[i] = run; run += v;
    }
    sums[t] = run; __syncthreads();
    for (int off = 1; off < 1024; off <<= 1) {
        int v = (t >= off) ? sums[t - off] : 0;
        __syncthreads();
        sums[t] += v;
        __syncthreads();
    }
    int offs = (t > 0) ? sums[t - 1] : 0;
#pragma unroll
    for (int i = 0; i < PER; ++i) {
        int idx = base + i;
        if (idx < n) { int v = offs + local[i]; rowp[idx] = v; cur[idx] = v; }
    }
    if (t == 0) rowp[n] = sums[1023];
}

// scatter: CSR src/dst lists + edge_attr rows -> CSR order, bf16, K-padded to 32
__global__ void scatter_kernel(const int* __restrict__ src, const int* __restrict__ dst,
                               int* __restrict__ cur, const float4* __restrict__ ea,
                               int* __restrict__ csrs, int* __restrict__ csrd,
                               ushort4* __restrict__ eacsr, int n) {
    int i = blockIdx.x * blockDim.x + threadIdx.x;
    if (i < n) {
        int d = dst[i];
        int p = atomicAdd(&cur[d], 1);
        csrs[p] = src[i];
        csrd[p] = d;
        const float4* er = ea + (size_t)i * 4;
        ushort4* eo = eacsr + (size_t)p * 8;
        const ushort4 z = make_ushort4(0, 0, 0, 0);
#pragma unroll
        for (int q = 0; q < 4; ++q) {
            float4 v = er[q];
            eo[q] = make_ushort4(f2bf(v.x), f2bf(v.y), f2bf(v.z), f2bf(v.w));
        }
#pragma unroll
        for (int q = 4; q < 8; ++q) eo[q] = z;
    }
}

// ---------------- bf16 MFMA GEMM: C = A@W^T + bias -> bf16 ----
template <bool RELU>
__global__ __launch_bounds__(256) void gemm_mfma_kernel(
    const unsigned short* __restrict__ A, const unsigned short* __restrict__ W,
    const float* __restrict__ bias0, const float* __restrict__ bias1, int bsplit,
    unsigned short* __restrict__ Cbf, int M, int N, int K) {
    const int t = threadIdx.x;
    const int wave = t >> 6, lane = t & 63;
    const int lo = lane & 15, quad = lane >> 4;
    const int m0 = blockIdx.y * 128 + wave * 32;
    const int n0 = blockIdx.x * 64;

    f32x4 acc[2][4];
#pragma unroll
    for (int i = 0; i < 2; ++i)
#pragma unroll
        for (int j = 0; j < 4; ++j) acc[i][j] = (f32x4){0.f, 0.f, 0.f, 0.f};

    for (int k0 = 0; k0 < K; k0 += 32) {
        bf16x8 af[2], bfr[4];
#pragma unroll
        for (int mi = 0; mi < 2; ++mi) {
            const int mb = m0 + mi * 16;
            af[mi] = (mb < M) ? *(const bf16x8*)(A + (size_t)(mb + lo) * K + k0 + quad * 8)
                              : (bf16x8){0, 0, 0, 0, 0, 0, 0, 0};
        }
#pragma unroll
        for (int ni = 0; ni < 4; ++ni)
            bfr[ni] = *(const bf16x8*)(W + (size_t)(n0 + ni * 16 + lo) * K + k0 + quad * 8);
#pragma unroll
        for (int mi = 0; mi < 2; ++mi)
#pragma unroll
            for (int ni = 0; ni < 4; ++ni)
                acc[mi][ni] = __builtin_amdgcn_mfma_f32_16x16x32_bf16(af[mi], bfr[ni], acc[mi][ni], 0, 0, 0);
    }

    float bn[4];
#pragma unroll
    for (int ni = 0; ni < 4; ++ni) {
        const int n = n0 + ni * 16 + lo;
        const float* bp = (n < bsplit) ? bias0 : bias1;
        const int bi = (n < bsplit) ? n : n - bsplit;
        bn[ni] = bp[bi];
    }
#pragma unroll
    for (int mi = 0; mi < 2; ++mi) {
        const int mb = m0 + mi * 16;
        if (mb >= M) continue;
#pragma unroll
        for (int ni = 0; ni < 4; ++ni) {
            const int n = n0 + ni * 16 + lo;
#pragma unroll
            for (int r = 0; r < 4; ++r) {
                float o = acc[mi][ni][r] + bn[ni];
                if (RELU) o = fmaxf(o, 0.f);
                Cbf[(size_t)(mb + quad * 4 + r) * N + n] = f2bf(o);
            }
        }
    }
}

// ---------------- FiLM gemm: hbf = bf16((a@Wg^T+gb)*h + (a@Wb^T+bb)), in place ----
__global__ __launch_bounds__(256) void gemm_film_kernel(
    const unsigned short* __restrict__ A, const unsigned short* __restrict__ Wg,
    const unsigned short* __restrict__ Wb, const float* __restrict__ gb,
    const float* __restrict__ bb, unsigned short* __restrict__ hbf, int M) {
    const int K = 128, N = 128;
    const int t = threadIdx.x;
    const int wave = t >> 6, lane = t & 63;
    const int lo = lane & 15, quad = lane >> 4;
    const int m0 = blockIdx.y * 128 + wave * 32;
    const int n0 = blockIdx.x * 64;

    f32x4 accg[2][4], accb[2][4];
#pragma unroll
    for (int i = 0; i < 2; ++i)
#pragma unroll
        for (int j = 0; j < 4; ++j) { accg[i][j] = (f32x4){0.f,0.f,0.f,0.f}; accb[i][j] = accg[i][j]; }

    for (int k0 = 0; k0 < K; k0 += 32) {
        bf16x8 af[2], bg4[4];
#pragma unroll
        for (int mi = 0; mi < 2; ++mi) {
            const int mb = m0 + mi * 16;
            af[mi] = (mb < M) ? *(const bf16x8*)(A + (size_t)(mb + lo) * K + k0 + quad * 8)
                              : (bf16x8){0,0,0,0,0,0,0,0};
        }
#pragma unroll
        for (int ni = 0; ni < 4; ++ni)
            bg4[ni] = *(const bf16x8*)(Wg + (size_t)(n0 + ni * 16 + lo) * K + k0 + quad * 8);
#pragma unroll
        for (int mi = 0; mi < 2; ++mi)
#pragma unroll
            for (int ni = 0; ni < 4; ++ni)
                accg[mi][ni] = __builtin_amdgcn_mfma_f32_16x16x32_bf16(af[mi], bg4[ni], accg[mi][ni], 0, 0, 0);
#pragma unroll
        for (int ni = 0; ni < 4; ++ni)
            bg4[ni] = *(const bf16x8*)(Wb + (size_t)(n0 + ni * 16 + lo) * K + k0 + quad * 8);
#pragma unroll
        for (int mi = 0; mi < 2; ++mi)
#pragma unroll
            for (int ni = 0; ni < 4; ++ni)
                accb[mi][ni] = __builtin_amdgcn_mfma_f32_16x16x32_bf16(af[mi], bg4[ni], accb[mi][ni], 0, 0, 0);
    }

#pragma unroll
    for (int mi = 0; mi < 2; ++mi) {
        const int mb = m0 + mi * 16;
        if (mb >= M) continue;
#pragma unroll
        for (int ni = 0; ni < 4; ++ni) {
            const int n = n0 + ni * 16 + lo;
            const float g = gb[n], b = bb[n];
#pragma unroll
            for (int r = 0; r < 4; ++r) {
                const size_t idx = (size_t)(mb + quad * 4 + r) * N + n;
                union { unsigned int i; float f; } hv; hv.i = (unsigned int)hbf[idx] << 16;
                hbf[idx] = f2bf((accg[mi][ni][r] + g) * hv.f + (accb[mi][ni][r] + b));
            }
        }
    }
}

// ---------------- q1 gemm + q2 head: atomicAdd(out, sum(relu(h@q1^T+b1)*q2w)) ----
__global__ __launch_bounds__(256) void gemm_q1_kernel(
    const unsigned short* __restrict__ A, const unsigned short* __restrict__ W,
    const float* __restrict__ q1b, const float* __restrict__ q2w,
    float* __restrict__ outsum, int M) {
    const int K = 128;
    const int t = threadIdx.x;
    const int wave = t >> 6, lane = t & 63;
    const int lo = lane & 15, quad = lane >> 4;
    const int m0 = blockIdx.y * 128 + wave * 32;
    const int n0 = blockIdx.x * 64;
    __shared__ float red[4];

    f32x4 acc[2][4];
#pragma unroll
    for (int i = 0; i < 2; ++i)
#pragma unroll
        for (int j = 0; j < 4; ++j) acc[i][j] = (f32x4){0.f, 0.f, 0.f, 0.f};

    for (int k0 = 0; k0 < K; k0 += 32) {
        bf16x8 af[2], bfr[4];
#pragma unroll
        for (int mi = 0; mi < 2; ++mi) {
            const int mb = m0 + mi * 16;
            af[mi] = (mb < M) ? *(const bf16x8*)(A + (size_t)(mb + lo) * K + k0 + quad * 8)
                              : (bf16x8){0,0,0,0,0,0,0,0};
        }
#pragma unroll
        for (int ni = 0; ni < 4; ++ni)
            bfr[ni] = *(const bf16x8*)(W + (size_t)(n0 + ni * 16 + lo) * K + k0 + quad * 8);
#pragma unroll
        for (int mi = 0; mi < 2; ++mi)
#pragma unroll
            for (int ni = 0; ni < 4; ++ni)
                acc[mi][ni] = __builtin_amdgcn_mfma_f32_16x16x32_bf16(af[mi], bfr[ni], acc[mi][ni], 0, 0, 0);
    }

    float partial = 0.f;
#pragma unroll
    for (int mi = 0; mi < 2; ++mi) {
        const int mb = m0 + mi * 16;
        if (mb >= M) continue;
#pragma unroll
        for (int ni = 0; ni < 4; ++ni) {
            const int n = n0 + ni * 16 + lo;
            const float b = q1b[n], w = q2w[n];
#pragma unroll
            for (int r = 0; r < 4; ++r)
                partial += fmaxf(acc[mi][ni][r] + b, 0.f) * w;
        }
    }
    partial += __shfl_xor(partial, 1);  partial += __shfl_xor(partial, 2);
    partial += __shfl_xor(partial, 4);  partial += __shfl_xor(partial, 8);
    partial += __shfl_xor(partial, 16); partial += __shfl_xor(partial, 32);
    if (lane == 0) red[wave] = partial;
    __syncthreads();
    if (t == 0) atomicAdd(outsum, red[0] + red[1] + red[2] + red[3]);
}

// ---------------- fp32 vector GEMM (only for ap: K=16) ----------------
template <int BK, bool RELU, bool WBF16>
__global__ __launch_bounds__(256) void gemm_kernel(const float* __restrict__ A,
                                                   const float* __restrict__ W,
                                                   const float* __restrict__ bp,
                                                   float* __restrict__ C,
                                                   unsigned short* __restrict__ Cbf,
                                                   int M, int N, int K) {
    __shared__ float As[BK][68];
    __shared__ float Ws[BK][68];
    const int t = threadIdx.x;
    const int m0 = blockIdx.y * 64;
    const int n0 = blockIdx.x * 64;
    const int tx = t & 15, ty = t >> 4;
    float acc[4][4];
#pragma unroll
    for (int i = 0; i < 4; ++i)
#pragma unroll
        for (int j = 0; j < 4; ++j) acc[i][j] = 0.f;

    for (int k0 = 0; k0 < K; k0 += BK) {
        const int r = t >> 2, cc = (t & 3) * 4;
        const int arow = m0 + r;
        float4 av = (arow < M) ? *(const float4*)(A + (size_t)arow * K + k0 + cc)
                               : make_float4(0.f, 0.f, 0.f, 0.f);
        As[cc + 0][r] = av.x; As[cc + 1][r] = av.y;
        As[cc + 2][r] = av.z; As[cc + 3][r] = av.w;
        float4 wv = *(const float4*)(W + (size_t)(n0 + r) * K + k0 + cc);
        Ws[cc + 0][r] = wv.x; Ws[cc + 1][r] = wv.y;
        Ws[cc + 2][r] = wv.z; Ws[cc + 3][r] = wv.w;
        __syncthreads();
#pragma unroll
        for (int k = 0; k < BK; ++k) {
            float4 a4 = *(const float4*)&As[k][ty * 4];
            float4 b4 = *(const float4*)&Ws[k][tx * 4];
            float a_[4] = {a4.x, a4.y, a4.z, a4.w};
            float b_[4] = {b4.x, b4.y, b4.z, b4.w};
#pragma unroll
            for (int i = 0; i < 4; ++i)
#pragma unroll
                for (int j = 0; j < 4; ++j) acc[i][j] += a_[i] * b_[j];
        }
        __syncthreads();
    }
    float4 bj = *(const float4*)(bp + n0 + tx * 4);
    float bb[4] = {bj.x, bj.y, bj.z, bj.w};
#pragma unroll
    for (int i = 0; i < 4; ++i) {
        int row = m0 + ty * 4 + i;
        if (row < M) {
            float o[4];
#pragma unroll
            for (int j = 0; j < 4; ++j) {
                o[j] = acc[i][j] + bb[j];
                if (RELU) o[j] = fmaxf(o[j], 0.f);
            }
            *(float4*)(C + (size_t)row * N + n0 + tx * 4) = make_float4(o[0], o[1], o[2], o[3]);
            if (WBF16)
                *(ushort4*)(Cbf + (size_t)row * N + n0 + tx * 4) =
                    make_ushort4(f2bf(o[0]), f2bf(o[1]), f2bf(o[2]), f2bf(o[3]));
        }
    }
}

// ---------------- fused GAT edge kernel ----------------
// Wave = 16 CSR positions (d sorted within batch). MFMA em-logit (as R8), then
// w = exp(min(logit,60)) (no max-sub; exact in softmax ratio), segmented
// shfl-scan over the sorted d-runs, one atomicAdd per run into num/den.
__global__ __launch_bounds__(256, 3) void gat_edge_kernel(
    const unsigned short* __restrict__ xfull,
    const int* __restrict__ csrs, const int* __restrict__ csrd,
    const unsigned short* __restrict__ eacsr, const unsigned short* __restrict__ wepad,
    const float* __restrict__ att, float* __restrict__ num, float* __restrict__ den, int E) {
    __shared__ float attl[256];
    const int tid = threadIdx.x;
    attl[tid] = att[tid];
    const int wave = tid >> 6, lane = tid & 63;
    const int lo = lane & 15, quad = lane >> 4;

    bf16x8 wef[16];
#pragma unroll
    for (int t = 0; t < 16; ++t)
        wef[t] = *(const bf16x8*)(wepad + (size_t)(t * 16 + lo) * 32 + quad * 8);
    __syncthreads();

    const int nb = (E + 15) / 16;
    for (int b = blockIdx.x * 4 + wave; b < nb; b += gridDim.x * 4) {
        const int p0 = b * 16;
        const bool valid = (p0 + lo) < E;
        const int p = valid ? (p0 + lo) : (E - 1);
        const int s = csrs[p], d = csrd[p];
        const bf16x8 eaf = *(const bf16x8*)(eacsr + (size_t)p * 32 + quad * 8);
        ushort4 xlc[16];                       // raw bf16 xl cache (32 VGPR)
        float ph0 = 0.f, ph1 = 0.f;
#pragma unroll
        for (int t = 0; t < 16; ++t) {
            f32x4 D = __builtin_amdgcn_mfma_f32_16x16x32_bf16(
                wef[t], eaf, (f32x4){0.f, 0.f, 0.f, 0.f}, 0, 0, 0);
            const int c0 = t * 16 + quad * 4;
            xlc[t] = *(const ushort4*)(xfull + (size_t)s * 512 + c0);
            const float4 xl4 = b4f(xlc[t]);
            const float4 xr4 = b4f(*(const ushort4*)(xfull + (size_t)d * 512 + 256 + c0));
            const float4 at4 = *(const float4*)&attl[c0];
            float vx = xl4.x + xr4.x + D[0];
            float vy = xl4.y + xr4.y + D[1];
            float vz = xl4.z + xr4.z + D[2];
            float vw = xl4.w + xr4.w + D[3];
            vx = fmaxf(vx, 0.2f * vx); vy = fmaxf(vy, 0.2f * vy);
            vz = fmaxf(vz, 0.2f * vz); vw = fmaxf(vw, 0.2f * vw);
            const float pt = vx * at4.x + vy * at4.y + vz * at4.z + vw * at4.w;
            if (t < 8) ph0 += pt; else ph1 += pt;
        }
        // complete per-edge logits (uniform across quads for each lo)
        ph0 += __shfl_xor(ph0, 16); ph0 += __shfl_xor(ph0, 32);
        ph1 += __shfl_xor(ph1, 16); ph1 += __shfl_xor(ph1, 32);
        const float e0 = valid ? __expf(fminf(ph0, 60.f)) : 0.f;
        const float e1 = valid ? __expf(fminf(ph1, 60.f)) : 0.f;

        // segmented-scan setup over sorted d within the 16-lane window
        bool take[4];
#pragma unroll
        for (int ki = 0; ki < 4; ++ki) {
            const int k = 1 << ki;
            take[ki] = (lo >= k) && (__shfl_up(d, k) == d);
        }
        const int dn = __shfl_down(d, 1);
        const bool tail = (lo == 15) || (dn != d);

        // den: scalar segmented scans (both heads, all quads; atomics from quad0/1)
        float s0 = e0, s1 = e1;
#pragma unroll
        for (int ki = 0; ki < 4; ++ki) {
            const int k = 1 << ki;
            const float t0 = __shfl_up(s0, k), t1 = __shfl_up(s1, k);
            if (take[ki]) { s0 += t0; s1 += t1; }
        }
        if (tail) {
            if (quad == 0) atomicAdd(&den[d * 2 + 0], s0);
            else if (quad == 1) atomicAdd(&den[d * 2 + 1], s1);
        }

        // num: per channel-block segmented scan of w*xl, one float4 atomic per run
#pragma unroll
        for (int t = 0; t < 16; ++t) {
            const float w = (t < 8) ? e0 : e1;
            const float4 xl4 = b4f(xlc[t]);
            float vx = w * xl4.x, vy = w * xl4.y, vz = w * xl4.z, vw = w * xl4.w;
#pragma unroll
            for (int ki = 0; ki < 4; ++ki) {
                const int k = 1 << ki;
                const float ux = __shfl_up(vx, k), uy = __shfl_up(vy, k);
                const float uz = __shfl_up(vz, k), uw = __shfl_up(vw, k);
                if (take[ki]) { vx += ux; vy += uy; vz += uz; vw += uw; }
            }
            if (tail) {
                float* np = num + (size_t)d * 256 + t * 16 + quad * 4;
                atomicAdd(np + 0, vx); atomicAdd(np + 1, vy);
                atomicAdd(np + 2, vz); atomicAdd(np + 3, vw);
            }
        }
    }
}

// ---------------- GAT epilogue: hbf = bf16(relu(mean_h(num/den) + bias)) ----
__global__ __launch_bounds__(256) void gat_fin_kernel(
    const float* __restrict__ num, const float* __restrict__ den,
    const float* __restrict__ bias, unsigned short* __restrict__ hbf, int nnodes) {
    const int gid = blockIdx.x * blockDim.x + threadIdx.x;
    const int node = gid >> 7, c = gid & 127;
    if (node >= nnodes) return;
    const float d0 = den[node * 2], d1 = den[node * 2 + 1];
    const float n0 = num[(size_t)node * 256 + c], n1 = num[(size_t)node * 256 + 128 + c];
    const float v0 = (d0 > 0.f) ? n0 / d0 : 0.f;
    const float v1 = (d1 > 0.f) ? n1 / d1 : 0.f;
    hbf[(size_t)node * 128 + c] = f2bf(fmaxf(0.5f * (v0 + v1) + bias[c], 0.f));
}

// ---------------- out = sum/N + q2_b ----------------
__global__ void final_kernel(const float* __restrict__ s, const float* __restrict__ q2b,
                             float* __restrict__ out, float invn) {
    out[0] = s[0] * invn + q2b[0];
}

extern "C" void kernel_launch(void* const* d_in, const int* in_sizes, int n_in,
                              void* d_out, int out_size, void* d_ws, size_t ws_size,
                              hipStream_t stream) {
    const int N = in_sizes[0] / 128;   // 20000
    const int E = in_sizes[1] / 2;     // 320000

    typedef const float* fp;
    fp x      = (fp)d_in[0];
    const int* ei = (const int*)d_in[1];
    fp ea     = (fp)d_in[2];
    fp action = (fp)d_in[3];
    fp inp_W  = (fp)d_in[4];
    fp inp_b  = (fp)d_in[5];
    fp ap_W = (fp)d_in[27], ap_b = (fp)d_in[28];
    fp g_W  = (fp)d_in[29], g_b  = (fp)d_in[30];
    fp be_W = (fp)d_in[31], be_b = (fp)d_in[32];
    fp q1_W = (fp)d_in[33], q1_b = (fp)d_in[34];
    fp q2_W = (fp)d_in[35], q2_b = (fp)d_in[36];

    char* base = (char*)d_ws;
    size_t off = 0;
    auto alloc = [&](size_t bytes) { char* p = base + off; off = (off + bytes + 255) & ~(size_t)255; return p; };
    unsigned short* xfb = (unsigned short*)alloc((size_t)N * 512 * 2);  // fused xl|xr bf16
    float* numden = (float*)alloc((size_t)N * 258 * 4);                 // num[N,256] + den[N,2]
    float* col  = (float*)alloc(128 * 4);
    int* deg    = (int*)alloc((size_t)N * 4);
    int* rowp   = (int*)alloc((size_t)(N + 1) * 4);
    int* cur    = (int*)alloc((size_t)N * 4);
    int* csrs   = (int*)alloc((size_t)E * 4);
    int* csrd   = (int*)alloc((size_t)E * 4);
    unsigned short* eacsr = (unsigned short*)alloc((size_t)E * 32 * 2); // ea bf16 K-pad, CSR order
    unsigned short* hbf = (unsigned short*)alloc((size_t)N * 128 * 2);
    unsigned short* xbf = (unsigned short*)alloc((size_t)N * 128 * 2);  // x bf16, later a bf16
    unsigned short* wbf = (unsigned short*)alloc((262144 + 3 * 8192) * 2);
    float* abuf = (float*)xfb;             // ap f32 out: xfb dead at FiLM stage
    unsigned short* abf = xbf;             // x_bf dead after inp gemm
    float* num = numden;
    float* den = numden + (size_t)N * 256;
    (void)ws_size; (void)n_in; (void)out_size;

    unsigned short* winp = wbf;            // 128x128
    unsigned short* w1l  = wbf + 16384;    // [512,128] fused pairs
    unsigned short* w1r  = w1l + 32768;
    unsigned short* w2l  = w1r + 32768;
    unsigned short* w2r  = w2l + 32768;
    unsigned short* wal  = w2r + 32768;
    unsigned short* war  = wal + 32768;
    unsigned short* wg   = war + 32768;    // 128x128
    unsigned short* wbe  = wg + 16384;
    unsigned short* wq1  = wbe + 16384;
    unsigned short* wep1 = wq1 + 16384;    // 3x [256,32] K-padded We
    unsigned short* wep2 = wep1 + 8192;
    unsigned short* wep3 = wep2 + 8192;

    const int* src = ei;
    const int* dst = ei + E;

    CvtDescs cd;
    int ce = 0;
    auto addc = [&](const float* s, unsigned short* d, int n) { cd.src[ce] = s; cd.dst[ce] = d; cd.n4[ce] = n / 4; ++ce; };
    addc(x, xbf, N * 128);
    addc(inp_W, winp, 16384);
    addc((fp)d_in[6],  w1l, 32768); addc((fp)d_in[8],  w1r, 32768);
    addc((fp)d_in[13], w2l, 32768); addc((fp)d_in[15], w2r, 32768);
    addc((fp)d_in[20], wal, 32768); addc((fp)d_in[22], war, 32768);
    addc(g_W, wg, 16384); addc(be_W, wbe, 16384); addc(q1_W, wq1, 16384);
    cd.cnt = ce;
    cvt_many_kernel<<<2048, 256, 0, stream>>>(cd);

    PadDescs pd;
    pd.src[0] = (fp)d_in[10]; pd.dst[0] = wep1; pd.rows[0] = 256;
    pd.src[1] = (fp)d_in[17]; pd.dst[1] = wep2; pd.rows[1] = 256;
    pd.src[2] = (fp)d_in[24]; pd.dst[2] = wep3; pd.rows[2] = 256;
    pd.cnt = 3;
    cvt_pad_kernel<<<64, 256, 0, stream>>>(pd);

    hipMemsetAsync(deg, 0, (size_t)N * 4, stream);
    hist_kernel<<<(E + 255) / 256, 256, 0, stream>>>(dst, deg, E);
    scan_kernel<<<1, 1024, 0, stream>>>(deg, rowp, cur, N);
    scatter_kernel<<<(E + 255) / 256, 256, 0, stream>>>(src, dst, cur, (const float4*)ea,
                                                        csrs, csrd, (ushort4*)eacsr, E);

    const int my = (N + 127) / 128;
    const int fing = (N * 128 + 255) / 256;

    auto run_gat = [&](const unsigned short* wep, const float* at, const float* bi) {
        hipMemsetAsync(numden, 0, (size_t)N * 258 * 4, stream);
        gat_edge_kernel<<<2500, 256, 0, stream>>>(xfb, csrs, csrd, eacsr, wep, at, num, den, E);
        gat_fin_kernel<<<fing, 256, 0, stream>>>(num, den, bi, hbf, N);
    };

    // h0 = relu(x @ inp_W^T + inp_b) -> bf16
    gemm_mfma_kernel<true><<<dim3(2, my), 256, 0, stream>>>(
        xbf, winp, inp_b, inp_b, 128, hbf, N, 128, 128);

    // s1
    gemm_mfma_kernel<false><<<dim3(8, my), 256, 0, stream>>>(
        hbf, w1l, (fp)d_in[7], (fp)d_in[9], 256, xfb, N, 512, 128);
    run_gat(wep1, (fp)d_in[11], (fp)d_in[12]);
    // s2
    gemm_mfma_kernel<false><<<dim3(8, my), 256, 0, stream>>>(
        hbf, w2l, (fp)d_in[14], (fp)d_in[16], 256, xfb, N, 512, 128);
    run_gat(wep2, (fp)d_in[18], (fp)d_in[19]);

    // FiLM: a = relu(action@ap^T+ap_b) -> abf; fused gamma/beta gemm in-place on hbf
    gemm_kernel<16, true, true><<<dim3(2, (N + 63) / 64), 256, 0, stream>>>(
        action, ap_W, ap_b, abuf, abf, N, 128, 16);
    gemm_film_kernel<<<dim3(2, my), 256, 0, stream>>>(abf, wg, wbe, g_b, be_b, hbf, N);

    // sa
    gemm_mfma_kernel<false><<<dim3(8, my), 256, 0, stream>>>(
        hbf, wal, (fp)d_in[21], (fp)d_in[23], 256, xfb, N, 512, 128);
    run_gat(wep3, (fp)d_in[25], (fp)d_in[26]);

    // q1 + q2 + mean fused
    hipMemsetAsync(col, 0, 4, stream);
    gemm_q1_kernel<<<dim3(2, my), 256, 0, stream>>>(hbf, wq1, q1_b, q2_W, col, N);
    final_kernel<<<1, 1, 0, stream>>>(col, q2_b, (float*)d_out, 1.0f / (float)N);
}

// Round 10
// 500.034 us; speedup vs baseline: 2.1411x; 2.1411x over previous
//
#include <hip/hip_runtime.h>
#include <hip/hip_bf16.h>

// EdgeAwareCritic: 3x GATv2 (H=2 heads, HID=128) + FiLM + MLP head, scalar output.
// fp32 inputs; GEMMs in bf16 MFMA. GAT per layer (R8 structure, R10 gathers):
//   K1: edge-parallel MFMA logits; xl/xr gathered in fp8 via cooperative WIDE
//       loads staged through LDS (4x fewer VMEM addresses than per-lane 4B).
//   K2: per-node exact softmax + weighted aggregate (bf16 gathers).
// FiLM fused into an in-place MFMA gemm; q1+q2+mean fused into one gemm.
// NOTE (R9 lesson): global f32 atomics as edge-accumulators cause ~300 MB HBM
// write amplification on 8-XCD MI355X — never again.

typedef __attribute__((ext_vector_type(8))) short bf16x8;   // 8 bf16 = 4 VGPR
typedef __attribute__((ext_vector_type(4))) float f32x4;
typedef __attribute__((ext_vector_type(2))) float f32x2;

__device__ __forceinline__ unsigned short f2bf(float f) {
    union { float f; unsigned int i; } v; v.f = f;
    unsigned int x = v.i;
    x += 0x7fffu + ((x >> 16) & 1u);   // round-to-nearest-even
    return (unsigned short)(x >> 16);
}
__device__ __forceinline__ float4 b4f(ushort4 u) {
    union { unsigned int i; float f; } a, b, c, d;
    a.i = (unsigned int)u.x << 16; b.i = (unsigned int)u.y << 16;
    c.i = (unsigned int)u.z << 16; d.i = (unsigned int)u.w << 16;
    return make_float4(a.f, b.f, c.f, d.f);
}
__device__ __forceinline__ unsigned char f2fp8(float f) {
    return (unsigned char)(__builtin_amdgcn_cvt_pk_fp8_f32(f, f, 0, false) & 0xFF);
}

// ---------------- multi-tensor fp32 -> bf16 convert (RNE) ----------------
#define MAXCVT 12
struct CvtDescs {
    const float* src[MAXCVT];
    unsigned short* dst[MAXCVT];
    int n4[MAXCVT];
    int cnt;
};
__global__ __launch_bounds__(256) void cvt_many_kernel(CvtDescs d) {
    const int tid = blockIdx.x * blockDim.x + threadIdx.x;
    const int stride = gridDim.x * blockDim.x;
    for (int e = 0; e < d.cnt; ++e) {
        const float4* s = (const float4*)d.src[e];
        ushort4* o = (ushort4*)d.dst[e];
        const int n = d.n4[e];
        for (int i = tid; i < n; i += stride) {
            float4 v = s[i];
            o[i] = make_ushort4(f2bf(v.x), f2bf(v.y), f2bf(v.z), f2bf(v.w));
        }
    }
}

// ---- row-pad convert: [rows,16] f32 -> [rows,32] bf16 (cols 16..31 = 0) ----
struct PadDescs {
    const float* src[4];
    unsigned short* dst[4];
    int rows[4];
    int cnt;
};
__global__ __launch_bounds__(256) void cvt_pad_kernel(PadDescs d) {
    const int tid = blockIdx.x * blockDim.x + threadIdx.x;
    const int stride = gridDim.x * blockDim.x;
    const ushort4 z = make_ushort4(0, 0, 0, 0);
    for (int e = 0; e < d.cnt; ++e) {
        const float4* s = (const float4*)d.src[e];
        ushort4* o = (ushort4*)d.dst[e];
        const int rows = d.rows[e];
        for (int r = tid; r < rows; r += stride) {
            const float4* sp = s + (size_t)r * 4;
            ushort4* op = o + (size_t)r * 8;
#pragma unroll
            for (int q = 0; q < 4; ++q) {
                float4 v = sp[q];
                op[q] = make_ushort4(f2bf(v.x), f2bf(v.y), f2bf(v.z), f2bf(v.w));
            }
#pragma unroll
            for (int q = 4; q < 8; ++q) op[q] = z;
        }
    }
}

// ---------------- CSR build ----------------
__global__ void hist_kernel(const int* __restrict__ dst, int* __restrict__ deg, int n) {
    int i = blockIdx.x * blockDim.x + threadIdx.x;
    if (i < n) atomicAdd(&deg[dst[i]], 1);
}

__global__ __launch_bounds__(1024) void scan_kernel(const int* __restrict__ deg,
                                                    int* __restrict__ rowp,
                                                    int* __restrict__ cur, int n) {
    __shared__ int sums[1024];
    const int t = threadIdx.x;
    const int PER = 20;
    int base = t * PER;
    int local[PER];
    int run = 0;
#pragma unroll
    for (int i = 0; i < PER; ++i) {
        int v = (base + i < n) ? deg[base + i] : 0;
        local[i] = run; run += v;
    }
    sums[t] = run; __syncthreads();
    for (int off = 1; off < 1024; off <<= 1) {
        int v = (t >= off) ? sums[t - off] : 0;
        __syncthreads();
        sums[t] += v;
        __syncthreads();
    }
    int offs = (t > 0) ? sums[t - 1] : 0;
#pragma unroll
    for (int i = 0; i < PER; ++i) {
        int idx = base + i;
        if (idx < n) { int v = offs + local[i]; rowp[idx] = v; cur[idx] = v; }
    }
    if (t == 0) rowp[n] = sums[1023];
}

// scatter: CSR src/dst lists + edge_attr rows -> CSR order, bf16, K-padded to 32
__global__ void scatter_kernel(const int* __restrict__ src, const int* __restrict__ dst,
                               int* __restrict__ cur, const float4* __restrict__ ea,
                               int* __restrict__ csrs, int* __restrict__ csrd,
                               ushort4* __restrict__ eacsr, int n) {
    int i = blockIdx.x * blockDim.x + threadIdx.x;
    if (i < n) {
        int d = dst[i];
        int p = atomicAdd(&cur[d], 1);
        csrs[p] = src[i];
        csrd[p] = d;
        const float4* er = ea + (size_t)i * 4;
        ushort4* eo = eacsr + (size_t)p * 8;
        const ushort4 z = make_ushort4(0, 0, 0, 0);
#pragma unroll
        for (int q = 0; q < 4; ++q) {
            float4 v = er[q];
            eo[q] = make_ushort4(f2bf(v.x), f2bf(v.y), f2bf(v.z), f2bf(v.w));
        }
#pragma unroll
        for (int q = 4; q < 8; ++q) eo[q] = z;
    }
}

// ---------------- bf16 MFMA GEMM: C = A@W^T + bias ----
// SPLIT=false: Cbf[M,N] bf16. SPLIT=true (N=512): Cbf[M,256] bf16 (cols<256) +
// Cf8[M,512] fp8 full width.
template <bool RELU, bool SPLIT>
__global__ __launch_bounds__(256) void gemm_mfma_kernel(
    const unsigned short* __restrict__ A, const unsigned short* __restrict__ W,
    const float* __restrict__ bias0, const float* __restrict__ bias1, int bsplit,
    unsigned short* __restrict__ Cbf, unsigned char* __restrict__ Cf8,
    int M, int N, int K) {
    const int t = threadIdx.x;
    const int wave = t >> 6, lane = t & 63;
    const int lo = lane & 15, quad = lane >> 4;
    const int m0 = blockIdx.y * 128 + wave * 32;
    const int n0 = blockIdx.x * 64;

    f32x4 acc[2][4];
#pragma unroll
    for (int i = 0; i < 2; ++i)
#pragma unroll
        for (int j = 0; j < 4; ++j) acc[i][j] = (f32x4){0.f, 0.f, 0.f, 0.f};

    for (int k0 = 0; k0 < K; k0 += 32) {
        bf16x8 af[2], bfr[4];
#pragma unroll
        for (int mi = 0; mi < 2; ++mi) {
            const int mb = m0 + mi * 16;
            af[mi] = (mb < M) ? *(const bf16x8*)(A + (size_t)(mb + lo) * K + k0 + quad * 8)
                              : (bf16x8){0, 0, 0, 0, 0, 0, 0, 0};
        }
#pragma unroll
        for (int ni = 0; ni < 4; ++ni)
            bfr[ni] = *(const bf16x8*)(W + (size_t)(n0 + ni * 16 + lo) * K + k0 + quad * 8);
#pragma unroll
        for (int mi = 0; mi < 2; ++mi)
#pragma unroll
            for (int ni = 0; ni < 4; ++ni)
                acc[mi][ni] = __builtin_amdgcn_mfma_f32_16x16x32_bf16(af[mi], bfr[ni], acc[mi][ni], 0, 0, 0);
    }

    float bn[4];
#pragma unroll
    for (int ni = 0; ni < 4; ++ni) {
        const int n = n0 + ni * 16 + lo;
        const float* bp = (n < bsplit) ? bias0 : bias1;
        const int bi = (n < bsplit) ? n : n - bsplit;
        bn[ni] = bp[bi];
    }
#pragma unroll
    for (int mi = 0; mi < 2; ++mi) {
        const int mb = m0 + mi * 16;
        if (mb >= M) continue;
#pragma unroll
        for (int ni = 0; ni < 4; ++ni) {
            const int n = n0 + ni * 16 + lo;
#pragma unroll
            for (int r = 0; r < 4; ++r) {
                float o = acc[mi][ni][r] + bn[ni];
                if (RELU) o = fmaxf(o, 0.f);
                const int row = mb + quad * 4 + r;
                if (SPLIT) {
                    if (n < 256) Cbf[(size_t)row * 256 + n] = f2bf(o);
                    Cf8[(size_t)row * 512 + n] = f2fp8(o);
                } else {
                    Cbf[(size_t)row * N + n] = f2bf(o);
                }
            }
        }
    }
}

// ---------------- FiLM gemm: hbf = bf16((a@Wg^T+gb)*h + (a@Wb^T+bb)), in place ----
__global__ __launch_bounds__(256) void gemm_film_kernel(
    const unsigned short* __restrict__ A, const unsigned short* __restrict__ Wg,
    const unsigned short* __restrict__ Wb, const float* __restrict__ gb,
    const float* __restrict__ bb, unsigned short* __restrict__ hbf, int M) {
    const int K = 128, N = 128;
    const int t = threadIdx.x;
    const int wave = t >> 6, lane = t & 63;
    const int lo = lane & 15, quad = lane >> 4;
    const int m0 = blockIdx.y * 128 + wave * 32;
    const int n0 = blockIdx.x * 64;

    f32x4 accg[2][4], accb[2][4];
#pragma unroll
    for (int i = 0; i < 2; ++i)
#pragma unroll
        for (int j = 0; j < 4; ++j) { accg[i][j] = (f32x4){0.f,0.f,0.f,0.f}; accb[i][j] = accg[i][j]; }

    for (int k0 = 0; k0 < K; k0 += 32) {
        bf16x8 af[2], bg4[4];
#pragma unroll
        for (int mi = 0; mi < 2; ++mi) {
            const int mb = m0 + mi * 16;
            af[mi] = (mb < M) ? *(const bf16x8*)(A + (size_t)(mb + lo) * K + k0 + quad * 8)
                              : (bf16x8){0,0,0,0,0,0,0,0};
        }
#pragma unroll
        for (int ni = 0; ni < 4; ++ni)
            bg4[ni] = *(const bf16x8*)(Wg + (size_t)(n0 + ni * 16 + lo) * K + k0 + quad * 8);
#pragma unroll
        for (int mi = 0; mi < 2; ++mi)
#pragma unroll
            for (int ni = 0; ni < 4; ++ni)
                accg[mi][ni] = __builtin_amdgcn_mfma_f32_16x16x32_bf16(af[mi], bg4[ni], accg[mi][ni], 0, 0, 0);
#pragma unroll
        for (int ni = 0; ni < 4; ++ni)
            bg4[ni] = *(const bf16x8*)(Wb + (size_t)(n0 + ni * 16 + lo) * K + k0 + quad * 8);
#pragma unroll
        for (int mi = 0; mi < 2; ++mi)
#pragma unroll
            for (int ni = 0; ni < 4; ++ni)
                accb[mi][ni] = __builtin_amdgcn_mfma_f32_16x16x32_bf16(af[mi], bg4[ni], accb[mi][ni], 0, 0, 0);
    }

#pragma unroll
    for (int mi = 0; mi < 2; ++mi) {
        const int mb = m0 + mi * 16;
        if (mb >= M) continue;
#pragma unroll
        for (int ni = 0; ni < 4; ++ni) {
            const int n = n0 + ni * 16 + lo;
            const float g = gb[n], b = bb[n];
#pragma unroll
            for (int r = 0; r < 4; ++r) {
                const size_t idx = (size_t)(mb + quad * 4 + r) * N + n;
                union { unsigned int i; float f; } hv; hv.i = (unsigned int)hbf[idx] << 16;
                hbf[idx] = f2bf((accg[mi][ni][r] + g) * hv.f + (accb[mi][ni][r] + b));
            }
        }
    }
}

// ---------------- q1 gemm + q2 head: atomicAdd(out, sum(relu(h@q1^T+b1)*q2w)) ----
__global__ __launch_bounds__(256) void gemm_q1_kernel(
    const unsigned short* __restrict__ A, const unsigned short* __restrict__ W,
    const float* __restrict__ q1b, const float* __restrict__ q2w,
    float* __restrict__ outsum, int M) {
    const int K = 128;
    const int t = threadIdx.x;
    const int wave = t >> 6, lane = t & 63;
    const int lo = lane & 15, quad = lane >> 4;
    const int m0 = blockIdx.y * 128 + wave * 32;
    const int n0 = blockIdx.x * 64;
    __shared__ float red[4];

    f32x4 acc[2][4];
#pragma unroll
    for (int i = 0; i < 2; ++i)
#pragma unroll
        for (int j = 0; j < 4; ++j) acc[i][j] = (f32x4){0.f, 0.f, 0.f, 0.f};

    for (int k0 = 0; k0 < K; k0 += 32) {
        bf16x8 af[2], bfr[4];
#pragma unroll
        for (int mi = 0; mi < 2; ++mi) {
            const int mb = m0 + mi * 16;
            af[mi] = (mb < M) ? *(const bf16x8*)(A + (size_t)(mb + lo) * K + k0 + quad * 8)
                              : (bf16x8){0,0,0,0,0,0,0,0};
        }
#pragma unroll
        for (int ni = 0; ni < 4; ++ni)
            bfr[ni] = *(const bf16x8*)(W + (size_t)(n0 + ni * 16 + lo) * K + k0 + quad * 8);
#pragma unroll
        for (int mi = 0; mi < 2; ++mi)
#pragma unroll
            for (int ni = 0; ni < 4; ++ni)
                acc[mi][ni] = __builtin_amdgcn_mfma_f32_16x16x32_bf16(af[mi], bfr[ni], acc[mi][ni], 0, 0, 0);
    }

    float partial = 0.f;
#pragma unroll
    for (int mi = 0; mi < 2; ++mi) {
        const int mb = m0 + mi * 16;
        if (mb >= M) continue;
#pragma unroll
        for (int ni = 0; ni < 4; ++ni) {
            const int n = n0 + ni * 16 + lo;
            const float b = q1b[n], w = q2w[n];
#pragma unroll
            for (int r = 0; r < 4; ++r)
                partial += fmaxf(acc[mi][ni][r] + b, 0.f) * w;
        }
    }
    partial += __shfl_xor(partial, 1);  partial += __shfl_xor(partial, 2);
    partial += __shfl_xor(partial, 4);  partial += __shfl_xor(partial, 8);
    partial += __shfl_xor(partial, 16); partial += __shfl_xor(partial, 32);
    if (lane == 0) red[wave] = partial;
    __syncthreads();
    if (t == 0) atomicAdd(outsum, red[0] + red[1] + red[2] + red[3]);
}

// ---------------- fp32 vector GEMM (only for ap: K=16) ----------------
template <int BK, bool RELU, bool WBF16>
__global__ __launch_bounds__(256) void gemm_kernel(const float* __restrict__ A,
                                                   const float* __restrict__ W,
                                                   const float* __restrict__ bp,
                                                   float* __restrict__ C,
                                                   unsigned short* __restrict__ Cbf,
                                                   int M, int N, int K) {
    __shared__ float As[BK][68];
    __shared__ float Ws[BK][68];
    const int t = threadIdx.x;
    const int m0 = blockIdx.y * 64;
    const int n0 = blockIdx.x * 64;
    const int tx = t & 15, ty = t >> 4;
    float acc[4][4];
#pragma unroll
    for (int i = 0; i < 4; ++i)
#pragma unroll
        for (int j = 0; j < 4; ++j) acc[i][j] = 0.f;

    for (int k0 = 0; k0 < K; k0 += BK) {
        const int r = t >> 2, cc = (t & 3) * 4;
        const int arow = m0 + r;
        float4 av = (arow < M) ? *(const float4*)(A + (size_t)arow * K + k0 + cc)
                               : make_float4(0.f, 0.f, 0.f, 0.f);
        As[cc + 0][r] = av.x; As[cc + 1][r] = av.y;
        As[cc + 2][r] = av.z; As[cc + 3][r] = av.w;
        float4 wv = *(const float4*)(W + (size_t)(n0 + r) * K + k0 + cc);
        Ws[cc + 0][r] = wv.x; Ws[cc + 1][r] = wv.y;
        Ws[cc + 2][r] = wv.z; Ws[cc + 3][r] = wv.w;
        __syncthreads();
#pragma unroll
        for (int k = 0; k < BK; ++k) {
            float4 a4 = *(const float4*)&As[k][ty * 4];
            float4 b4 = *(const float4*)&Ws[k][tx * 4];
            float a_[4] = {a4.x, a4.y, a4.z, a4.w};
            float b_[4] = {b4.x, b4.y, b4.z, b4.w};
#pragma unroll
            for (int i = 0; i < 4; ++i)
#pragma unroll
                for (int j = 0; j < 4; ++j) acc[i][j] += a_[i] * b_[j];
        }
        __syncthreads();
    }
    float4 bj = *(const float4*)(bp + n0 + tx * 4);
    float bb[4] = {bj.x, bj.y, bj.z, bj.w};
#pragma unroll
    for (int i = 0; i < 4; ++i) {
        int row = m0 + ty * 4 + i;
        if (row < M) {
            float o[4];
#pragma unroll
            for (int j = 0; j < 4; ++j) {
                o[j] = acc[i][j] + bb[j];
                if (RELU) o[j] = fmaxf(o[j], 0.f);
            }
            *(float4*)(C + (size_t)row * N + n0 + tx * 4) = make_float4(o[0], o[1], o[2], o[3]);
            if (WBF16)
                *(ushort4*)(Cbf + (size_t)row * N + n0 + tx * 4) =
                    make_ushort4(f2bf(o[0]), f2bf(o[1]), f2bf(o[2]), f2bf(o[3]));
        }
    }
}

// ---------------- GAT K1: MFMA edge logits, LDS-staged wide fp8 gathers ----
// Wave = 16 CSR positions/batch. Stage: 4 lanes/row load dwordx4 pieces of the
// edge's xl row (xf8[s][0:256]) and xr row (xf8[d][256:512]) into LDS (stride
// 272 B: 2-way bank aliasing only). Then 16x MFMA (A=WePad, B=eaCSR) + per-
// channel adds from LDS + shfl reduce -> logits. Uniform trip count for syncs.
#define LSTR 272
__global__ __launch_bounds__(256, 4) void gat_logit_kernel(
    const unsigned char* __restrict__ xf8,
    const int* __restrict__ csrs, const int* __restrict__ csrd,
    const unsigned short* __restrict__ eacsr, const unsigned short* __restrict__ wepad,
    const float* __restrict__ att, float* __restrict__ logit, int E) {
    __shared__ float attl[256];
    __shared__ __align__(16) unsigned char xls[4][16 * LSTR];
    __shared__ __align__(16) unsigned char xrs[4][16 * LSTR];
    const int tid = threadIdx.x;
    attl[tid] = att[tid];
    const int wave = tid >> 6, lane = tid & 63;
    const int lo = lane & 15, quad = lane >> 4;
    const int sr_row = lane >> 2, c16 = (lane & 3) * 16;

    bf16x8 wef[16];
#pragma unroll
    for (int t = 0; t < 16; ++t)
        wef[t] = *(const bf16x8*)(wepad + (size_t)(t * 16 + lo) * 32 + quad * 8);

    const int nb = (E + 15) / 16;
    const int wstride = gridDim.x * 4;
    const int trips = (nb + wstride - 1) / wstride;
    for (int it = 0; it < trips; ++it) {
        const int b = blockIdx.x * 4 + wave + it * wstride;
        const bool vb = b < nb;
        const int p0 = vb ? b * 16 : 0;
        if (vb) {
            const int pr = min(p0 + sr_row, E - 1);
            const int sr = csrs[pr], dr = csrd[pr];
            const unsigned char* xs = xf8 + (size_t)sr * 512 + c16;
            const unsigned char* xrp = xf8 + (size_t)dr * 512 + 256 + c16;
            unsigned char* ld = &xls[wave][sr_row * LSTR + c16];
            unsigned char* rd = &xrs[wave][sr_row * LSTR + c16];
#pragma unroll
            for (int j = 0; j < 4; ++j) {
                *(int4*)(ld + j * 64) = *(const int4*)(xs + j * 64);
                *(int4*)(rd + j * 64) = *(const int4*)(xrp + j * 64);
            }
        }
        __syncthreads();
        if (vb) {
            const bool valid = (p0 + lo) < E;
            const int p = valid ? (p0 + lo) : (E - 1);
            const bf16x8 eaf = *(const bf16x8*)(eacsr + (size_t)p * 32 + quad * 8);
            float ph0 = 0.f, ph1 = 0.f;
#pragma unroll
            for (int t = 0; t < 16; ++t) {
                f32x4 D = __builtin_amdgcn_mfma_f32_16x16x32_bf16(
                    wef[t], eaf, (f32x4){0.f, 0.f, 0.f, 0.f}, 0, 0, 0);
                const int c0 = t * 16 + quad * 4;
                const unsigned int xlu = *(const unsigned int*)&xls[wave][lo * LSTR + c0];
                const unsigned int xru = *(const unsigned int*)&xrs[wave][lo * LSTR + c0];
                const f32x2 l01 = __builtin_amdgcn_cvt_pk_f32_fp8(xlu, false);
                const f32x2 l23 = __builtin_amdgcn_cvt_pk_f32_fp8(xlu, true);
                const f32x2 r01 = __builtin_amdgcn_cvt_pk_f32_fp8(xru, false);
                const f32x2 r23 = __builtin_amdgcn_cvt_pk_f32_fp8(xru, true);
                const float4 at4 = *(const float4*)&attl[c0];
                float vx = l01.x + r01.x + D[0];
                float vy = l01.y + r01.y + D[1];
                float vz = l23.x + r23.x + D[2];
                float vw = l23.y + r23.y + D[3];
                vx = fmaxf(vx, 0.2f * vx); vy = fmaxf(vy, 0.2f * vy);
                vz = fmaxf(vz, 0.2f * vz); vw = fmaxf(vw, 0.2f * vw);
                const float pt = vx * at4.x + vy * at4.y + vz * at4.z + vw * at4.w;
                if (t < 8) ph0 += pt; else ph1 += pt;
            }
            ph0 += __shfl_xor(ph0, 16); ph0 += __shfl_xor(ph0, 32);
            ph1 += __shfl_xor(ph1, 16); ph1 += __shfl_xor(ph1, 32);
            if (valid) {
                if (quad == 0) logit[p0 + lo] = ph0;
                else if (quad == 1) logit[(size_t)E + p0 + lo] = ph1;
            }
        }
        __syncthreads();
    }
}

// ---------------- GAT K2: per-node softmax + weighted gather-sum (bf16) ----
// xlb: [N,256] bf16 (xl half only).
__global__ __launch_bounds__(256) void gat_na_kernel(
    const unsigned short* __restrict__ xlb,
    const int* __restrict__ rowp, const int* __restrict__ csrs,
    const float* __restrict__ wgt, const float* __restrict__ bias,
    unsigned short* __restrict__ houtb, int nnodes, int E) {
    const int lane = threadIdx.x & 63;
    const int node = blockIdx.x * 4 + (threadIdx.x >> 6);
    if (node >= nnodes) return;
    const int rs = rowp[node], re = rowp[node + 1];
    const int h = lane >> 5, l = lane & 31;
    const float* lg = wgt + (size_t)h * E;

    float mx = -INFINITY;
    for (int i = rs + l; i < re; i += 32) mx = fmaxf(mx, lg[i]);
    mx = fmaxf(mx, __shfl_xor(mx, 1));  mx = fmaxf(mx, __shfl_xor(mx, 2));
    mx = fmaxf(mx, __shfl_xor(mx, 4));  mx = fmaxf(mx, __shfl_xor(mx, 8));
    mx = fmaxf(mx, __shfl_xor(mx, 16));
    float sum = 0.f;
    for (int i = rs + l; i < re; i += 32) sum += __expf(lg[i] - mx);
    sum += __shfl_xor(sum, 1);  sum += __shfl_xor(sum, 2);  sum += __shfl_xor(sum, 4);
    sum += __shfl_xor(sum, 8);  sum += __shfl_xor(sum, 16);
    const float inv = (re > rs) ? 1.f / sum : 0.f;

    float4 acc0 = make_float4(0.f, 0.f, 0.f, 0.f), acc1 = acc0;
    int i = rs;
    for (; i + 1 < re; i += 2) {
        const int s0 = csrs[i], s1 = csrs[i + 1];
        const float w0 = __expf(lg[i] - mx) * inv;
        const float w1 = __expf(lg[i + 1] - mx) * inv;
        const float4 x0 = b4f(*(const ushort4*)(xlb + (size_t)s0 * 256 + 4 * lane));
        const float4 x1 = b4f(*(const ushort4*)(xlb + (size_t)s1 * 256 + 4 * lane));
        acc0.x += w0 * x0.x; acc0.y += w0 * x0.y; acc0.z += w0 * x0.z; acc0.w += w0 * x0.w;
        acc1.x += w1 * x1.x; acc1.y += w1 * x1.y; acc1.z += w1 * x1.z; acc1.w += w1 * x1.w;
    }
    if (i < re) {
        const int s0 = csrs[i];
        const float w0 = __expf(lg[i] - mx) * inv;
        const float4 x0 = b4f(*(const ushort4*)(xlb + (size_t)s0 * 256 + 4 * lane));
        acc0.x += w0 * x0.x; acc0.y += w0 * x0.y; acc0.z += w0 * x0.z; acc0.w += w0 * x0.w;
    }
    float ox = acc0.x + acc1.x, oy = acc0.y + acc1.y;
    float oz = acc0.z + acc1.z, ow = acc0.w + acc1.w;
    ox += __shfl_xor(ox, 32); oy += __shfl_xor(oy, 32);
    oz += __shfl_xor(oz, 32); ow += __shfl_xor(ow, 32);
    if (lane < 32) {
        float4 bu = *(const float4*)(bias + 4 * lane);
        *(ushort4*)(houtb + (size_t)node * 128 + 4 * lane) = make_ushort4(
            f2bf(fmaxf(0.5f * ox + bu.x, 0.f)), f2bf(fmaxf(0.5f * oy + bu.y, 0.f)),
            f2bf(fmaxf(0.5f * oz + bu.z, 0.f)), f2bf(fmaxf(0.5f * ow + bu.w, 0.f)));
    }
}

// ---------------- out = sum/N + q2_b ----------------
__global__ void final_kernel(const float* __restrict__ s, const float* __restrict__ q2b,
                             float* __restrict__ out, float invn) {
    out[0] = s[0] * invn + q2b[0];
}

extern "C" void kernel_launch(void* const* d_in, const int* in_sizes, int n_in,
                              void* d_out, int out_size, void* d_ws, size_t ws_size,
                              hipStream_t stream) {
    const int N = in_sizes[0] / 128;   // 20000
    const int E = in_sizes[1] / 2;     // 320000

    typedef const float* fp;
    fp x      = (fp)d_in[0];
    const int* ei = (const int*)d_in[1];
    fp ea     = (fp)d_in[2];
    fp action = (fp)d_in[3];
    fp inp_W  = (fp)d_in[4];
    fp inp_b  = (fp)d_in[5];
    fp ap_W = (fp)d_in[27], ap_b = (fp)d_in[28];
    fp g_W  = (fp)d_in[29], g_b  = (fp)d_in[30];
    fp be_W = (fp)d_in[31], be_b = (fp)d_in[32];
    fp q1_W = (fp)d_in[33], q1_b = (fp)d_in[34];
    fp q2_W = (fp)d_in[35], q2_b = (fp)d_in[36];

    char* base = (char*)d_ws;
    size_t off = 0;
    auto alloc = [&](size_t bytes) { char* p = base + off; off = (off + bytes + 255) & ~(size_t)255; return p; };
    unsigned short* xfb = (unsigned short*)alloc((size_t)N * 256 * 2);  // xl half bf16
    unsigned char*  xf8 = (unsigned char*)alloc((size_t)N * 512);       // full row fp8
    float* col  = (float*)alloc(128 * 4);
    int* deg    = (int*)alloc((size_t)N * 4);
    int* rowp   = (int*)alloc((size_t)(N + 1) * 4);
    int* cur    = (int*)alloc((size_t)N * 4);
    int* csrs   = (int*)alloc((size_t)E * 4);
    int* csrd   = (int*)alloc((size_t)E * 4);
    unsigned short* eacsr = (unsigned short*)alloc((size_t)E * 32 * 2); // ea bf16 K-pad, CSR order
    float* wgt  = (float*)alloc((size_t)2 * E * 4);                     // logits
    unsigned short* hbf = (unsigned short*)alloc((size_t)N * 128 * 2);
    unsigned short* xbf = (unsigned short*)alloc((size_t)N * 128 * 2);  // x bf16, later a bf16
    unsigned short* wbf = (unsigned short*)alloc((262144 + 3 * 8192) * 2);
    float* abuf = (float*)xfb;             // ap f32 out [N,128]: fits xfb, dead at FiLM stage
    unsigned short* abf = xbf;             // x_bf dead after inp gemm
    (void)ws_size; (void)n_in; (void)out_size;

    unsigned short* winp = wbf;            // 128x128
    unsigned short* w1l  = wbf + 16384;    // [512,128] fused pairs
    unsigned short* w1r  = w1l + 32768;
    unsigned short* w2l  = w1r + 32768;
    unsigned short* w2r  = w2l + 32768;
    unsigned short* wal  = w2r + 32768;
    unsigned short* war  = wal + 32768;
    unsigned short* wg   = war + 32768;    // 128x128
    unsigned short* wbe  = wg + 16384;
    unsigned short* wq1  = wbe + 16384;
    unsigned short* wep1 = wq1 + 16384;    // 3x [256,32] K-padded We
    unsigned short* wep2 = wep1 + 8192;
    unsigned short* wep3 = wep2 + 8192;

    const int* src = ei;
    const int* dst = ei + E;

    CvtDescs cd;
    int ce = 0;
    auto addc = [&](const float* s, unsigned short* d, int n) { cd.src[ce] = s; cd.dst[ce] = d; cd.n4[ce] = n / 4; ++ce; };
    addc(x, xbf, N * 128);
    addc(inp_W, winp, 16384);
    addc((fp)d_in[6],  w1l, 32768); addc((fp)d_in[8],  w1r, 32768);
    addc((fp)d_in[13], w2l, 32768); addc((fp)d_in[15], w2r, 32768);
    addc((fp)d_in[20], wal, 32768); addc((fp)d_in[22], war, 32768);
    addc(g_W, wg, 16384); addc(be_W, wbe, 16384); addc(q1_W, wq1, 16384);
    cd.cnt = ce;
    cvt_many_kernel<<<2048, 256, 0, stream>>>(cd);

    PadDescs pd;
    pd.src[0] = (fp)d_in[10]; pd.dst[0] = wep1; pd.rows[0] = 256;
    pd.src[1] = (fp)d_in[17]; pd.dst[1] = wep2; pd.rows[1] = 256;
    pd.src[2] = (fp)d_in[24]; pd.dst[2] = wep3; pd.rows[2] = 256;
    pd.cnt = 3;
    cvt_pad_kernel<<<64, 256, 0, stream>>>(pd);

    hipMemsetAsync(deg, 0, (size_t)N * 4, stream);
    hist_kernel<<<(E + 255) / 256, 256, 0, stream>>>(dst, deg, E);
    scan_kernel<<<1, 1024, 0, stream>>>(deg, rowp, cur, N);
    scatter_kernel<<<(E + 255) / 256, 256, 0, stream>>>(src, dst, cur, (const float4*)ea,
                                                        csrs, csrd, (ushort4*)eacsr, E);

    const int my = (N + 127) / 128;
    const int nodeg = (N + 3) / 4;

    auto run_gat = [&](const unsigned short* wep, const float* at, const float* bi,
                       unsigned short* hb) {
        gat_logit_kernel<<<2048, 256, 0, stream>>>(xf8, csrs, csrd, eacsr, wep, at, wgt, E);
        gat_na_kernel<<<nodeg, 256, 0, stream>>>(xfb, rowp, csrs, wgt, bi, hb, N, E);
    };

    // h0 = relu(x @ inp_W^T + inp_b) -> bf16
    gemm_mfma_kernel<true, false><<<dim3(2, my), 256, 0, stream>>>(
        xbf, winp, inp_b, inp_b, 128, hbf, nullptr, N, 128, 128);

    // s1
    gemm_mfma_kernel<false, true><<<dim3(8, my), 256, 0, stream>>>(
        hbf, w1l, (fp)d_in[7], (fp)d_in[9], 256, xfb, xf8, N, 512, 128);
    run_gat(wep1, (fp)d_in[11], (fp)d_in[12], hbf);
    // s2
    gemm_mfma_kernel<false, true><<<dim3(8, my), 256, 0, stream>>>(
        hbf, w2l, (fp)d_in[14], (fp)d_in[16], 256, xfb, xf8, N, 512, 128);
    run_gat(wep2, (fp)d_in[18], (fp)d_in[19], hbf);

    // FiLM: a = relu(action@ap^T+ap_b) -> abf; fused gamma/beta gemm in-place on hbf
    gemm_kernel<16, true, true><<<dim3(2, (N + 63) / 64), 256, 0, stream>>>(
        action, ap_W, ap_b, abuf, abf, N, 128, 16);
    gemm_film_kernel<<<dim3(2, my), 256, 0, stream>>>(abf, wg, wbe, g_b, be_b, hbf, N);

    // sa
    gemm_mfma_kernel<false, true><<<dim3(8, my), 256, 0, stream>>>(
        hbf, wal, (fp)d_in[21], (fp)d_in[23], 256, xfb, xf8, N, 512, 128);
    run_gat(wep3, (fp)d_in[25], (fp)d_in[26], hbf);

    // q1 + q2 + mean fused
    hipMemsetAsync(col, 0, 4, stream);
    gemm_q1_kernel<<<dim3(2, my), 256, 0, stream>>>(hbf, wq1, q1_b, q2_W, col, N);
    final_kernel<<<1, 1, 0, stream>>>(col, q2_b, (float*)d_out, 1.0f / (float)N);
}

// Round 11
// 469.283 us; speedup vs baseline: 2.2814x; 1.0655x over previous
//
#include <hip/hip_runtime.h>
#include <hip/hip_bf16.h>

// EdgeAwareCritic: 3x GATv2 (H=2 heads, HID=128) + FiLM + MLP head, scalar output.
// fp32 inputs; GEMMs in bf16 MFMA. GAT per layer (R10 structure):
//   K1: edge-parallel MFMA logits; xl/xr fp8 via LDS-staged wide loads.
//   K2: per-node exact softmax + weighted aggregate (fp8 gathers, f32 accum).
// ea/We stored unpadded K=16; MFMA upper-K zeros synthesized in registers.
// NOTE (R9 lesson): global f32 atomics as edge-accumulators cause ~300 MB HBM
// write amplification on 8-XCD MI355X — never again.

typedef __attribute__((ext_vector_type(8))) short bf16x8;   // 8 bf16 = 4 VGPR
typedef __attribute__((ext_vector_type(4))) float f32x4;
typedef __attribute__((ext_vector_type(2))) float f32x2;

#define ZERO8 ((bf16x8){0, 0, 0, 0, 0, 0, 0, 0})

__device__ __forceinline__ unsigned short f2bf(float f) {
    union { float f; unsigned int i; } v; v.f = f;
    unsigned int x = v.i;
    x += 0x7fffu + ((x >> 16) & 1u);   // round-to-nearest-even
    return (unsigned short)(x >> 16);
}
__device__ __forceinline__ unsigned char f2fp8(float f) {
    return (unsigned char)(__builtin_amdgcn_cvt_pk_fp8_f32(f, f, 0, false) & 0xFF);
}

// ---------------- multi-tensor fp32 -> bf16 convert (RNE) ----------------
#define MAXCVT 16
struct CvtDescs {
    const float* src[MAXCVT];
    unsigned short* dst[MAXCVT];
    int n4[MAXCVT];
    int cnt;
};
__global__ __launch_bounds__(256) void cvt_many_kernel(CvtDescs d) {
    const int tid = blockIdx.x * blockDim.x + threadIdx.x;
    const int stride = gridDim.x * blockDim.x;
    for (int e = 0; e < d.cnt; ++e) {
        const float4* s = (const float4*)d.src[e];
        ushort4* o = (ushort4*)d.dst[e];
        const int n = d.n4[e];
        for (int i = tid; i < n; i += stride) {
            float4 v = s[i];
            o[i] = make_ushort4(f2bf(v.x), f2bf(v.y), f2bf(v.z), f2bf(v.w));
        }
    }
}

// ---------------- CSR build ----------------
__global__ void hist_kernel(const int* __restrict__ dst, int* __restrict__ deg, int n) {
    int i = blockIdx.x * blockDim.x + threadIdx.x;
    if (i < n) atomicAdd(&deg[dst[i]], 1);
}

__global__ __launch_bounds__(1024) void scan_kernel(const int* __restrict__ deg,
                                                    int* __restrict__ rowp,
                                                    int* __restrict__ cur, int n) {
    __shared__ int sums[1024];
    const int t = threadIdx.x;
    const int PER = 20;
    int base = t * PER;
    int local[PER];
    int run = 0;
#pragma unroll
    for (int i = 0; i < PER; ++i) {
        int v = (base + i < n) ? deg[base + i] : 0;
        local[i] = run; run += v;
    }
    sums[t] = run; __syncthreads();
    for (int off = 1; off < 1024; off <<= 1) {
        int v = (t >= off) ? sums[t - off] : 0;
        __syncthreads();
        sums[t] += v;
        __syncthreads();
    }
    int offs = (t > 0) ? sums[t - 1] : 0;
#pragma unroll
    for (int i = 0; i < PER; ++i) {
        int idx = base + i;
        if (idx < n) { int v = offs + local[i]; rowp[idx] = v; cur[idx] = v; }
    }
    if (t == 0) rowp[n] = sums[1023];
}

// scatter: CSR src/dst lists + edge_attr rows -> CSR order bf16 (unpadded, 32 B)
__global__ void scatter_kernel(const int* __restrict__ src, const int* __restrict__ dst,
                               int* __restrict__ cur, const float4* __restrict__ ea,
                               int* __restrict__ csrs, int* __restrict__ csrd,
                               ushort4* __restrict__ eacsr, int n) {
    int i = blockIdx.x * blockDim.x + threadIdx.x;
    if (i < n) {
        int d = dst[i];
        int p = atomicAdd(&cur[d], 1);
        csrs[p] = src[i];
        csrd[p] = d;
        const float4* er = ea + (size_t)i * 4;
        ushort4* eo = eacsr + (size_t)p * 4;
#pragma unroll
        for (int q = 0; q < 4; ++q) {
            float4 v = er[q];
            eo[q] = make_ushort4(f2bf(v.x), f2bf(v.y), f2bf(v.z), f2bf(v.w));
        }
    }
}

// ---------------- bf16 MFMA GEMM: C = A@W^T + bias ----
// SPLIT=false: Cbf[M,N] bf16. SPLIT=true (N=512): Cf8[M,512] fp8 only.
template <bool RELU, bool SPLIT>
__global__ __launch_bounds__(256) void gemm_mfma_kernel(
    const unsigned short* __restrict__ A, const unsigned short* __restrict__ W,
    const float* __restrict__ bias0, const float* __restrict__ bias1, int bsplit,
    unsigned short* __restrict__ Cbf, unsigned char* __restrict__ Cf8,
    int M, int N, int K) {
    const int t = threadIdx.x;
    const int wave = t >> 6, lane = t & 63;
    const int lo = lane & 15, quad = lane >> 4;
    const int m0 = blockIdx.y * 128 + wave * 32;
    const int n0 = blockIdx.x * 64;

    f32x4 acc[2][4];
#pragma unroll
    for (int i = 0; i < 2; ++i)
#pragma unroll
        for (int j = 0; j < 4; ++j) acc[i][j] = (f32x4){0.f, 0.f, 0.f, 0.f};

    for (int k0 = 0; k0 < K; k0 += 32) {
        bf16x8 af[2], bfr[4];
#pragma unroll
        for (int mi = 0; mi < 2; ++mi) {
            const int mb = m0 + mi * 16;
            af[mi] = (mb < M) ? *(const bf16x8*)(A + (size_t)(mb + lo) * K + k0 + quad * 8)
                              : ZERO8;
        }
#pragma unroll
        for (int ni = 0; ni < 4; ++ni)
            bfr[ni] = *(const bf16x8*)(W + (size_t)(n0 + ni * 16 + lo) * K + k0 + quad * 8);
#pragma unroll
        for (int mi = 0; mi < 2; ++mi)
#pragma unroll
            for (int ni = 0; ni < 4; ++ni)
                acc[mi][ni] = __builtin_amdgcn_mfma_f32_16x16x32_bf16(af[mi], bfr[ni], acc[mi][ni], 0, 0, 0);
    }

    float bn[4];
#pragma unroll
    for (int ni = 0; ni < 4; ++ni) {
        const int n = n0 + ni * 16 + lo;
        const float* bp = (n < bsplit) ? bias0 : bias1;
        const int bi = (n < bsplit) ? n : n - bsplit;
        bn[ni] = bp[bi];
    }
#pragma unroll
    for (int mi = 0; mi < 2; ++mi) {
        const int mb = m0 + mi * 16;
        if (mb >= M) continue;
#pragma unroll
        for (int ni = 0; ni < 4; ++ni) {
            const int n = n0 + ni * 16 + lo;
#pragma unroll
            for (int r = 0; r < 4; ++r) {
                float o = acc[mi][ni][r] + bn[ni];
                if (RELU) o = fmaxf(o, 0.f);
                const int row = mb + quad * 4 + r;
                if (SPLIT) Cf8[(size_t)row * 512 + n] = f2fp8(o);
                else       Cbf[(size_t)row * N + n] = f2bf(o);
            }
        }
    }
}

// ---------------- FiLM gemm: hbf = bf16((a@Wg^T+gb)*h + (a@Wb^T+bb)), in place ----
__global__ __launch_bounds__(256) void gemm_film_kernel(
    const unsigned short* __restrict__ A, const unsigned short* __restrict__ Wg,
    const unsigned short* __restrict__ Wb, const float* __restrict__ gb,
    const float* __restrict__ bb, unsigned short* __restrict__ hbf, int M) {
    const int K = 128, N = 128;
    const int t = threadIdx.x;
    const int wave = t >> 6, lane = t & 63;
    const int lo = lane & 15, quad = lane >> 4;
    const int m0 = blockIdx.y * 128 + wave * 32;
    const int n0 = blockIdx.x * 64;

    f32x4 accg[2][4], accb[2][4];
#pragma unroll
    for (int i = 0; i < 2; ++i)
#pragma unroll
        for (int j = 0; j < 4; ++j) { accg[i][j] = (f32x4){0.f,0.f,0.f,0.f}; accb[i][j] = accg[i][j]; }

    for (int k0 = 0; k0 < K; k0 += 32) {
        bf16x8 af[2], bg4[4];
#pragma unroll
        for (int mi = 0; mi < 2; ++mi) {
            const int mb = m0 + mi * 16;
            af[mi] = (mb < M) ? *(const bf16x8*)(A + (size_t)(mb + lo) * K + k0 + quad * 8)
                              : ZERO8;
        }
#pragma unroll
        for (int ni = 0; ni < 4; ++ni)
            bg4[ni] = *(const bf16x8*)(Wg + (size_t)(n0 + ni * 16 + lo) * K + k0 + quad * 8);
#pragma unroll
        for (int mi = 0; mi < 2; ++mi)
#pragma unroll
            for (int ni = 0; ni < 4; ++ni)
                accg[mi][ni] = __builtin_amdgcn_mfma_f32_16x16x32_bf16(af[mi], bg4[ni], accg[mi][ni], 0, 0, 0);
#pragma unroll
        for (int ni = 0; ni < 4; ++ni)
            bg4[ni] = *(const bf16x8*)(Wb + (size_t)(n0 + ni * 16 + lo) * K + k0 + quad * 8);
#pragma unroll
        for (int mi = 0; mi < 2; ++mi)
#pragma unroll
            for (int ni = 0; ni < 4; ++ni)
                accb[mi][ni] = __builtin_amdgcn_mfma_f32_16x16x32_bf16(af[mi], bg4[ni], accb[mi][ni], 0, 0, 0);
    }

#pragma unroll
    for (int mi = 0; mi < 2; ++mi) {
        const int mb = m0 + mi * 16;
        if (mb >= M) continue;
#pragma unroll
        for (int ni = 0; ni < 4; ++ni) {
            const int n = n0 + ni * 16 + lo;
            const float g = gb[n], b = bb[n];
#pragma unroll
            for (int r = 0; r < 4; ++r) {
                const size_t idx = (size_t)(mb + quad * 4 + r) * N + n;
                union { unsigned int i; float f; } hv; hv.i = (unsigned int)hbf[idx] << 16;
                hbf[idx] = f2bf((accg[mi][ni][r] + g) * hv.f + (accb[mi][ni][r] + b));
            }
        }
    }
}

// ---------------- q1 gemm + q2 head: atomicAdd(out, sum(relu(h@q1^T+b1)*q2w)) ----
__global__ __launch_bounds__(256) void gemm_q1_kernel(
    const unsigned short* __restrict__ A, const unsigned short* __restrict__ W,
    const float* __restrict__ q1b, const float* __restrict__ q2w,
    float* __restrict__ outsum, int M) {
    const int K = 128;
    const int t = threadIdx.x;
    const int wave = t >> 6, lane = t & 63;
    const int lo = lane & 15, quad = lane >> 4;
    const int m0 = blockIdx.y * 128 + wave * 32;
    const int n0 = blockIdx.x * 64;
    __shared__ float red[4];

    f32x4 acc[2][4];
#pragma unroll
    for (int i = 0; i < 2; ++i)
#pragma unroll
        for (int j = 0; j < 4; ++j) acc[i][j] = (f32x4){0.f, 0.f, 0.f, 0.f};

    for (int k0 = 0; k0 < K; k0 += 32) {
        bf16x8 af[2], bfr[4];
#pragma unroll
        for (int mi = 0; mi < 2; ++mi) {
            const int mb = m0 + mi * 16;
            af[mi] = (mb < M) ? *(const bf16x8*)(A + (size_t)(mb + lo) * K + k0 + quad * 8)
                              : ZERO8;
        }
#pragma unroll
        for (int ni = 0; ni < 4; ++ni)
            bfr[ni] = *(const bf16x8*)(W + (size_t)(n0 + ni * 16 + lo) * K + k0 + quad * 8);
#pragma unroll
        for (int mi = 0; mi < 2; ++mi)
#pragma unroll
            for (int ni = 0; ni < 4; ++ni)
                acc[mi][ni] = __builtin_amdgcn_mfma_f32_16x16x32_bf16(af[mi], bfr[ni], acc[mi][ni], 0, 0, 0);
    }

    float partial = 0.f;
#pragma unroll
    for (int mi = 0; mi < 2; ++mi) {
        const int mb = m0 + mi * 16;
        if (mb >= M) continue;
#pragma unroll
        for (int ni = 0; ni < 4; ++ni) {
            const int n = n0 + ni * 16 + lo;
            const float b = q1b[n], w = q2w[n];
#pragma unroll
            for (int r = 0; r < 4; ++r)
                partial += fmaxf(acc[mi][ni][r] + b, 0.f) * w;
        }
    }
    partial += __shfl_xor(partial, 1);  partial += __shfl_xor(partial, 2);
    partial += __shfl_xor(partial, 4);  partial += __shfl_xor(partial, 8);
    partial += __shfl_xor(partial, 16); partial += __shfl_xor(partial, 32);
    if (lane == 0) red[wave] = partial;
    __syncthreads();
    if (t == 0) atomicAdd(outsum, red[0] + red[1] + red[2] + red[3]);
}

// ---------------- fp32 vector GEMM (only for ap: K=16) -> bf16 out ----------------
template <int BK, bool RELU>
__global__ __launch_bounds__(256) void gemm_kernel(const float* __restrict__ A,
                                                   const float* __restrict__ W,
                                                   const float* __restrict__ bp,
                                                   unsigned short* __restrict__ Cbf,
                                                   int M, int N, int K) {
    __shared__ float As[BK][68];
    __shared__ float Ws[BK][68];
    const int t = threadIdx.x;
    const int m0 = blockIdx.y * 64;
    const int n0 = blockIdx.x * 64;
    const int tx = t & 15, ty = t >> 4;
    float acc[4][4];
#pragma unroll
    for (int i = 0; i < 4; ++i)
#pragma unroll
        for (int j = 0; j < 4; ++j) acc[i][j] = 0.f;

    for (int k0 = 0; k0 < K; k0 += BK) {
        const int r = t >> 2, cc = (t & 3) * 4;
        const int arow = m0 + r;
        float4 av = (arow < M) ? *(const float4*)(A + (size_t)arow * K + k0 + cc)
                               : make_float4(0.f, 0.f, 0.f, 0.f);
        As[cc + 0][r] = av.x; As[cc + 1][r] = av.y;
        As[cc + 2][r] = av.z; As[cc + 3][r] = av.w;
        float4 wv = *(const float4*)(W + (size_t)(n0 + r) * K + k0 + cc);
        Ws[cc + 0][r] = wv.x; Ws[cc + 1][r] = wv.y;
        Ws[cc + 2][r] = wv.z; Ws[cc + 3][r] = wv.w;
        __syncthreads();
#pragma unroll
        for (int k = 0; k < BK; ++k) {
            float4 a4 = *(const float4*)&As[k][ty * 4];
            float4 b4 = *(const float4*)&Ws[k][tx * 4];
            float a_[4] = {a4.x, a4.y, a4.z, a4.w};
            float b_[4] = {b4.x, b4.y, b4.z, b4.w};
#pragma unroll
            for (int i = 0; i < 4; ++i)
#pragma unroll
                for (int j = 0; j < 4; ++j) acc[i][j] += a_[i] * b_[j];
        }
        __syncthreads();
    }
    float4 bj = *(const float4*)(bp + n0 + tx * 4);
    float bb[4] = {bj.x, bj.y, bj.z, bj.w};
#pragma unroll
    for (int i = 0; i < 4; ++i) {
        int row = m0 + ty * 4 + i;
        if (row < M) {
            float o[4];
#pragma unroll
            for (int j = 0; j < 4; ++j) {
                o[j] = acc[i][j] + bb[j];
                if (RELU) o[j] = fmaxf(o[j], 0.f);
            }
            *(ushort4*)(Cbf + (size_t)row * N + n0 + tx * 4) =
                make_ushort4(f2bf(o[0]), f2bf(o[1]), f2bf(o[2]), f2bf(o[3]));
        }
    }
}

// ---------------- GAT K1: MFMA edge logits, LDS-staged wide fp8 gathers ----
// Wave = 16 CSR positions/batch. Stage: 4 lanes/row load dwordx4 pieces of the
// edge's xl row (xf8[s][0:256]) and xr row (xf8[d][256:512]) into LDS. Then
// 16x MFMA (A=We rows, B=ea row; upper-K zeros in registers) + adds + reduce.
#define LSTR 272
__global__ __launch_bounds__(256, 4) void gat_logit_kernel(
    const unsigned char* __restrict__ xf8,
    const int* __restrict__ csrs, const int* __restrict__ csrd,
    const unsigned short* __restrict__ eacsr, const unsigned short* __restrict__ we16,
    const float* __restrict__ att, float* __restrict__ logit, int E) {
    __shared__ float attl[256];
    __shared__ __align__(16) unsigned char xls[4][16 * LSTR];
    __shared__ __align__(16) unsigned char xrs[4][16 * LSTR];
    const int tid = threadIdx.x;
    attl[tid] = att[tid];
    const int wave = tid >> 6, lane = tid & 63;
    const int lo = lane & 15, quad = lane >> 4;
    const int sr_row = lane >> 2, c16 = (lane & 3) * 16;

    bf16x8 wef[16];
#pragma unroll
    for (int t = 0; t < 16; ++t)
        wef[t] = (quad < 2) ? *(const bf16x8*)(we16 + (size_t)(t * 16 + lo) * 16 + quad * 8)
                            : ZERO8;

    const int nb = (E + 15) / 16;
    const int wstride = gridDim.x * 4;
    const int trips = (nb + wstride - 1) / wstride;
    for (int it = 0; it < trips; ++it) {
        const int b = blockIdx.x * 4 + wave + it * wstride;
        const bool vb = b < nb;
        const int p0 = vb ? b * 16 : 0;
        if (vb) {
            const int pr = min(p0 + sr_row, E - 1);
            const int sr = csrs[pr], dr = csrd[pr];
            const unsigned char* xs = xf8 + (size_t)sr * 512 + c16;
            const unsigned char* xrp = xf8 + (size_t)dr * 512 + 256 + c16;
            unsigned char* ld = &xls[wave][sr_row * LSTR + c16];
            unsigned char* rd = &xrs[wave][sr_row * LSTR + c16];
#pragma unroll
            for (int j = 0; j < 4; ++j) {
                *(int4*)(ld + j * 64) = *(const int4*)(xs + j * 64);
                *(int4*)(rd + j * 64) = *(const int4*)(xrp + j * 64);
            }
        }
        __syncthreads();
        if (vb) {
            const bool valid = (p0 + lo) < E;
            const int p = valid ? (p0 + lo) : (E - 1);
            const bf16x8 eaf = (quad < 2)
                ? *(const bf16x8*)(eacsr + (size_t)p * 16 + quad * 8) : ZERO8;
            float ph0 = 0.f, ph1 = 0.f;
#pragma unroll
            for (int t = 0; t < 16; ++t) {
                f32x4 D = __builtin_amdgcn_mfma_f32_16x16x32_bf16(
                    wef[t], eaf, (f32x4){0.f, 0.f, 0.f, 0.f}, 0, 0, 0);
                const int c0 = t * 16 + quad * 4;
                const unsigned int xlu = *(const unsigned int*)&xls[wave][lo * LSTR + c0];
                const unsigned int xru = *(const unsigned int*)&xrs[wave][lo * LSTR + c0];
                const f32x2 l01 = __builtin_amdgcn_cvt_pk_f32_fp8(xlu, false);
                const f32x2 l23 = __builtin_amdgcn_cvt_pk_f32_fp8(xlu, true);
                const f32x2 r01 = __builtin_amdgcn_cvt_pk_f32_fp8(xru, false);
                const f32x2 r23 = __builtin_amdgcn_cvt_pk_f32_fp8(xru, true);
                const float4 at4 = *(const float4*)&attl[c0];
                float vx = l01.x + r01.x + D[0];
                float vy = l01.y + r01.y + D[1];
                float vz = l23.x + r23.x + D[2];
                float vw = l23.y + r23.y + D[3];
                vx = fmaxf(vx, 0.2f * vx); vy = fmaxf(vy, 0.2f * vy);
                vz = fmaxf(vz, 0.2f * vz); vw = fmaxf(vw, 0.2f * vw);
                const float pt = vx * at4.x + vy * at4.y + vz * at4.z + vw * at4.w;
                if (t < 8) ph0 += pt; else ph1 += pt;
            }
            ph0 += __shfl_xor(ph0, 16); ph0 += __shfl_xor(ph0, 32);
            ph1 += __shfl_xor(ph1, 16); ph1 += __shfl_xor(ph1, 32);
            if (valid) {
                if (quad == 0) logit[p0 + lo] = ph0;
                else if (quad == 1) logit[(size_t)E + p0 + lo] = ph1;
            }
        }
        __syncthreads();
    }
}

// ---------------- GAT K2: per-node softmax + weighted gather-sum (fp8) ----
// xf8: [N,512] fp8; lane owns 4 channels (byte offset 4*lane, cols 0..255=xl).
__global__ __launch_bounds__(256) void gat_na_kernel(
    const unsigned char* __restrict__ xf8,
    const int* __restrict__ rowp, const int* __restrict__ csrs,
    const float* __restrict__ wgt, const float* __restrict__ bias,
    unsigned short* __restrict__ houtb, int nnodes, int E) {
    const int lane = threadIdx.x & 63;
    const int node = blockIdx.x * 4 + (threadIdx.x >> 6);
    if (node >= nnodes) return;
    const int rs = rowp[node], re = rowp[node + 1];
    const int h = lane >> 5, l = lane & 31;
    const float* lg = wgt + (size_t)h * E;

    float mx = -INFINITY;
    for (int i = rs + l; i < re; i += 32) mx = fmaxf(mx, lg[i]);
    mx = fmaxf(mx, __shfl_xor(mx, 1));  mx = fmaxf(mx, __shfl_xor(mx, 2));
    mx = fmaxf(mx, __shfl_xor(mx, 4));  mx = fmaxf(mx, __shfl_xor(mx, 8));
    mx = fmaxf(mx, __shfl_xor(mx, 16));
    float sum = 0.f;
    for (int i = rs + l; i < re; i += 32) sum += __expf(lg[i] - mx);
    sum += __shfl_xor(sum, 1);  sum += __shfl_xor(sum, 2);  sum += __shfl_xor(sum, 4);
    sum += __shfl_xor(sum, 8);  sum += __shfl_xor(sum, 16);
    const float inv = (re > rs) ? 1.f / sum : 0.f;

    float4 acc0 = make_float4(0.f, 0.f, 0.f, 0.f), acc1 = acc0;
    int i = rs;
    for (; i + 1 < re; i += 2) {
        const int s0 = csrs[i], s1 = csrs[i + 1];
        const float w0 = __expf(lg[i] - mx) * inv;
        const float w1 = __expf(lg[i + 1] - mx) * inv;
        const unsigned int u0 = *(const unsigned int*)(xf8 + (size_t)s0 * 512 + 4 * lane);
        const unsigned int u1 = *(const unsigned int*)(xf8 + (size_t)s1 * 512 + 4 * lane);
        const f32x2 a01 = __builtin_amdgcn_cvt_pk_f32_fp8(u0, false);
        const f32x2 a23 = __builtin_amdgcn_cvt_pk_f32_fp8(u0, true);
        const f32x2 b01 = __builtin_amdgcn_cvt_pk_f32_fp8(u1, false);
        const f32x2 b23 = __builtin_amdgcn_cvt_pk_f32_fp8(u1, true);
        acc0.x += w0 * a01.x; acc0.y += w0 * a01.y; acc0.z += w0 * a23.x; acc0.w += w0 * a23.y;
        acc1.x += w1 * b01.x; acc1.y += w1 * b01.y; acc1.z += w1 * b23.x; acc1.w += w1 * b23.y;
    }
    if (i < re) {
        const int s0 = csrs[i];
        const float w0 = __expf(lg[i] - mx) * inv;
        const unsigned int u0 = *(const unsigned int*)(xf8 + (size_t)s0 * 512 + 4 * lane);
        const f32x2 a01 = __builtin_amdgcn_cvt_pk_f32_fp8(u0, false);
        const f32x2 a23 = __builtin_amdgcn_cvt_pk_f32_fp8(u0, true);
        acc0.x += w0 * a01.x; acc0.y += w0 * a01.y; acc0.z += w0 * a23.x; acc0.w += w0 * a23.y;
    }
    float ox = acc0.x + acc1.x, oy = acc0.y + acc1.y;
    float oz = acc0.z + acc1.z, ow = acc0.w + acc1.w;
    // mean over heads: lane l (head0) pairs with lane l^32 (head1, same channels)
    ox += __shfl_xor(ox, 32); oy += __shfl_xor(oy, 32);
    oz += __shfl_xor(oz, 32); ow += __shfl_xor(ow, 32);
    if (lane < 32) {
        float4 bu = *(const float4*)(bias + 4 * lane);
        *(ushort4*)(houtb + (size_t)node * 128 + 4 * lane) = make_ushort4(
            f2bf(fmaxf(0.5f * ox + bu.x, 0.f)), f2bf(fmaxf(0.5f * oy + bu.y, 0.f)),
            f2bf(fmaxf(0.5f * oz + bu.z, 0.f)), f2bf(fmaxf(0.5f * ow + bu.w, 0.f)));
    }
}

// ---------------- out = sum/N + q2_b ----------------
__global__ void final_kernel(const float* __restrict__ s, const float* __restrict__ q2b,
                             float* __restrict__ out, float invn) {
    out[0] = s[0] * invn + q2b[0];
}

extern "C" void kernel_launch(void* const* d_in, const int* in_sizes, int n_in,
                              void* d_out, int out_size, void* d_ws, size_t ws_size,
                              hipStream_t stream) {
    const int N = in_sizes[0] / 128;   // 20000
    const int E = in_sizes[1] / 2;     // 320000

    typedef const float* fp;
    fp x      = (fp)d_in[0];
    const int* ei = (const int*)d_in[1];
    fp ea     = (fp)d_in[2];
    fp action = (fp)d_in[3];
    fp inp_W  = (fp)d_in[4];
    fp inp_b  = (fp)d_in[5];
    fp ap_W = (fp)d_in[27], ap_b = (fp)d_in[28];
    fp g_W  = (fp)d_in[29], g_b  = (fp)d_in[30];
    fp be_W = (fp)d_in[31], be_b = (fp)d_in[32];
    fp q1_W = (fp)d_in[33], q1_b = (fp)d_in[34];
    fp q2_W = (fp)d_in[35], q2_b = (fp)d_in[36];

    char* base = (char*)d_ws;
    size_t off = 0;
    auto alloc = [&](size_t bytes) { char* p = base + off; off = (off + bytes + 255) & ~(size_t)255; return p; };
    unsigned char*  xf8 = (unsigned char*)alloc((size_t)N * 512);       // xl|xr fp8
    float* col  = (float*)alloc(128 * 4);
    int* deg    = (int*)alloc((size_t)N * 4);
    int* rowp   = (int*)alloc((size_t)(N + 1) * 4);
    int* cur    = (int*)alloc((size_t)N * 4);
    int* csrs   = (int*)alloc((size_t)E * 4);
    int* csrd   = (int*)alloc((size_t)E * 4);
    unsigned short* eacsr = (unsigned short*)alloc((size_t)E * 16 * 2); // ea bf16 CSR order
    float* wgt  = (float*)alloc((size_t)2 * E * 4);                     // logits
    unsigned short* hbf = (unsigned short*)alloc((size_t)N * 128 * 2);
    unsigned short* xbf = (unsigned short*)alloc((size_t)N * 128 * 2);  // x bf16, later a bf16
    unsigned short* wbf = (unsigned short*)alloc((262144 + 3 * 4096) * 2);
    unsigned short* abf = xbf;             // x_bf dead after inp gemm
    (void)ws_size; (void)n_in; (void)out_size;

    unsigned short* winp = wbf;            // 128x128
    unsigned short* w1l  = wbf + 16384;    // [512,128] fused pairs
    unsigned short* w1r  = w1l + 32768;
    unsigned short* w2l  = w1r + 32768;
    unsigned short* w2r  = w2l + 32768;
    unsigned short* wal  = w2r + 32768;
    unsigned short* war  = wal + 32768;
    unsigned short* wg   = war + 32768;    // 128x128
    unsigned short* wbe  = wg + 16384;
    unsigned short* wq1  = wbe + 16384;
    unsigned short* wep1 = wq1 + 16384;    // 3x [256,16] bf16 We (unpadded)
    unsigned short* wep2 = wep1 + 4096;
    unsigned short* wep3 = wep2 + 4096;

    const int* src = ei;
    const int* dst = ei + E;

    CvtDescs cd;
    int ce = 0;
    auto addc = [&](const float* s, unsigned short* d, int n) { cd.src[ce] = s; cd.dst[ce] = d; cd.n4[ce] = n / 4; ++ce; };
    addc(x, xbf, N * 128);
    addc(inp_W, winp, 16384);
    addc((fp)d_in[6],  w1l, 32768); addc((fp)d_in[8],  w1r, 32768);
    addc((fp)d_in[13], w2l, 32768); addc((fp)d_in[15], w2r, 32768);
    addc((fp)d_in[20], wal, 32768); addc((fp)d_in[22], war, 32768);
    addc(g_W, wg, 16384); addc(be_W, wbe, 16384); addc(q1_W, wq1, 16384);
    addc((fp)d_in[10], wep1, 4096); addc((fp)d_in[17], wep2, 4096); addc((fp)d_in[24], wep3, 4096);
    cd.cnt = ce;
    cvt_many_kernel<<<2048, 256, 0, stream>>>(cd);

    hipMemsetAsync(deg, 0, (size_t)N * 4, stream);
    hist_kernel<<<(E + 255) / 256, 256, 0, stream>>>(dst, deg, E);
    scan_kernel<<<1, 1024, 0, stream>>>(deg, rowp, cur, N);
    scatter_kernel<<<(E + 255) / 256, 256, 0, stream>>>(src, dst, cur, (const float4*)ea,
                                                        csrs, csrd, (ushort4*)eacsr, E);

    const int my = (N + 127) / 128;
    const int nodeg = (N + 3) / 4;

    auto run_gat = [&](const unsigned short* wep, const float* at, const float* bi,
                       unsigned short* hb) {
        gat_logit_kernel<<<2048, 256, 0, stream>>>(xf8, csrs, csrd, eacsr, wep, at, wgt, E);
        gat_na_kernel<<<nodeg, 256, 0, stream>>>(xf8, rowp, csrs, wgt, bi, hb, N, E);
    };

    // h0 = relu(x @ inp_W^T + inp_b) -> bf16
    gemm_mfma_kernel<true, false><<<dim3(2, my), 256, 0, stream>>>(
        xbf, winp, inp_b, inp_b, 128, hbf, nullptr, N, 128, 128);

    // s1
    gemm_mfma_kernel<false, true><<<dim3(8, my), 256, 0, stream>>>(
        hbf, w1l, (fp)d_in[7], (fp)d_in[9], 256, nullptr, xf8, N, 512, 128);
    run_gat(wep1, (fp)d_in[11], (fp)d_in[12], hbf);
    // s2
    gemm_mfma_kernel<false, true><<<dim3(8, my), 256, 0, stream>>>(
        hbf, w2l, (fp)d_in[14], (fp)d_in[16], 256, nullptr, xf8, N, 512, 128);
    run_gat(wep2, (fp)d_in[18], (fp)d_in[19], hbf);

    // FiLM: a = relu(action@ap^T+ap_b) -> abf; fused gamma/beta gemm in-place on hbf
    gemm_kernel<16, true><<<dim3(2, (N + 63) / 64), 256, 0, stream>>>(
        action, ap_W, ap_b, abf, N, 128, 16);
    gemm_film_kernel<<<dim3(2, my), 256, 0, stream>>>(abf, wg, wbe, g_b, be_b, hbf, N);

    // sa
    gemm_mfma_kernel<false, true><<<dim3(8, my), 256, 0, stream>>>(
        hbf, wal, (fp)d_in[21], (fp)d_in[23], 256, nullptr, xf8, N, 512, 128);
    run_gat(wep3, (fp)d_in[25], (fp)d_in[26], hbf);

    // q1 + q2 + mean fused
    hipMemsetAsync(col, 0, 4, stream);
    gemm_q1_kernel<<<dim3(2, my), 256, 0, stream>>>(hbf, wq1, q1_b, q2_W, col, N);
    final_kernel<<<1, 1, 0, stream>>>(col, q2_b, (float*)d_out, 1.0f / (float)N);
}

// Round 12
// 460.020 us; speedup vs baseline: 2.3273x; 1.0201x over previous
//
#include <hip/hip_runtime.h>
#include <hip/hip_bf16.h>

// EdgeAwareCritic: 3x GATv2 (H=2 heads, HID=128) + FiLM + MLP head, scalar output.
// fp32 inputs; GEMMs in bf16 MFMA. GAT per layer:
//   K1: edge-parallel MFMA logits; xl/xr fp8 via LDS-staged wide loads
//       (wave-private slices -> wave-level waits, no block barriers).
//   K2: per-node exact softmax + weighted aggregate (fp8 gathers, f32 accum).
// NOTE (R9 lesson): global f32 atomics as edge-accumulators cause ~300 MB HBM
// write amplification on 8-XCD MI355X — never again.

typedef __attribute__((ext_vector_type(8))) short bf16x8;   // 8 bf16 = 4 VGPR
typedef __attribute__((ext_vector_type(4))) float f32x4;
typedef __attribute__((ext_vector_type(2))) float f32x2;

#define ZERO8 ((bf16x8){0, 0, 0, 0, 0, 0, 0, 0})

__device__ __forceinline__ unsigned short f2bf(float f) {
    union { float f; unsigned int i; } v; v.f = f;
    unsigned int x = v.i;
    x += 0x7fffu + ((x >> 16) & 1u);   // round-to-nearest-even
    return (unsigned short)(x >> 16);
}
__device__ __forceinline__ unsigned char f2fp8(float f) {
    return (unsigned char)(__builtin_amdgcn_cvt_pk_fp8_f32(f, f, 0, false) & 0xFF);
}
__device__ __forceinline__ void wave_lds_fence() {
    // LDS slices are wave-private: order ds_write -> ds_read within the wave.
    __builtin_amdgcn_wave_barrier();
    asm volatile("s_waitcnt lgkmcnt(0)" ::: "memory");
    __builtin_amdgcn_wave_barrier();
}

// ---------------- multi-tensor fp32 -> bf16 convert (RNE) ----------------
#define MAXCVT 16
struct CvtDescs {
    const float* src[MAXCVT];
    unsigned short* dst[MAXCVT];
    int n4[MAXCVT];
    int cnt;
};
__global__ __launch_bounds__(256) void cvt_many_kernel(CvtDescs d) {
    const int tid = blockIdx.x * blockDim.x + threadIdx.x;
    const int stride = gridDim.x * blockDim.x;
    for (int e = 0; e < d.cnt; ++e) {
        const float4* s = (const float4*)d.src[e];
        ushort4* o = (ushort4*)d.dst[e];
        const int n = d.n4[e];
        for (int i = tid; i < n; i += stride) {
            float4 v = s[i];
            o[i] = make_ushort4(f2bf(v.x), f2bf(v.y), f2bf(v.z), f2bf(v.w));
        }
    }
}

// ---------------- CSR build ----------------
__global__ void hist_kernel(const int* __restrict__ dst, int* __restrict__ deg, int n) {
    int i = blockIdx.x * blockDim.x + threadIdx.x;
    if (i < n) atomicAdd(&deg[dst[i]], 1);
}

__global__ __launch_bounds__(1024) void scan_kernel(const int* __restrict__ deg,
                                                    int* __restrict__ rowp,
                                                    int* __restrict__ cur, int n) {
    __shared__ int sums[1024];
    const int t = threadIdx.x;
    const int PER = 20;
    int base = t * PER;
    int local[PER];
    int run = 0;
#pragma unroll
    for (int i = 0; i < PER; ++i) {
        int v = (base + i < n) ? deg[base + i] : 0;
        local[i] = run; run += v;
    }
    sums[t] = run; __syncthreads();
    for (int off = 1; off < 1024; off <<= 1) {
        int v = (t >= off) ? sums[t - off] : 0;
        __syncthreads();
        sums[t] += v;
        __syncthreads();
    }
    int offs = (t > 0) ? sums[t - 1] : 0;
#pragma unroll
    for (int i = 0; i < PER; ++i) {
        int idx = base + i;
        if (idx < n) { int v = offs + local[i]; rowp[idx] = v; cur[idx] = v; }
    }
    if (t == 0) rowp[n] = sums[1023];
}

// scatter: CSR src/dst lists + edge_attr rows -> CSR order bf16 (unpadded, 32 B)
__global__ void scatter_kernel(const int* __restrict__ src, const int* __restrict__ dst,
                               int* __restrict__ cur, const float4* __restrict__ ea,
                               int* __restrict__ csrs, int* __restrict__ csrd,
                               ushort4* __restrict__ eacsr, int n) {
    int i = blockIdx.x * blockDim.x + threadIdx.x;
    if (i < n) {
        int d = dst[i];
        int p = atomicAdd(&cur[d], 1);
        csrs[p] = src[i];
        csrd[p] = d;
        const float4* er = ea + (size_t)i * 4;
        ushort4* eo = eacsr + (size_t)p * 4;
#pragma unroll
        for (int q = 0; q < 4; ++q) {
            float4 v = er[q];
            eo[q] = make_ushort4(f2bf(v.x), f2bf(v.y), f2bf(v.z), f2bf(v.w));
        }
    }
}

// ---------------- bf16 MFMA GEMM: C = A@W^T + bias ----
// SPLIT=false: Cbf[M,N] bf16. SPLIT=true (N=512): Cf8[M,512] fp8 via LDS-staged
// wide stores. AF32: A is fp32, converted in-kernel.
template <bool RELU, bool SPLIT, bool AF32>
__global__ __launch_bounds__(256) void gemm_mfma_kernel(
    const void* __restrict__ Ap, const unsigned short* __restrict__ W,
    const float* __restrict__ bias0, const float* __restrict__ bias1, int bsplit,
    unsigned short* __restrict__ Cbf, unsigned char* __restrict__ Cf8,
    int M, int N, int K) {
    __shared__ unsigned char ctile[SPLIT ? 128 * 64 : 64];
    const int t = threadIdx.x;
    const int wave = t >> 6, lane = t & 63;
    const int lo = lane & 15, quad = lane >> 4;
    const int m0 = blockIdx.y * 128 + wave * 32;
    const int n0 = blockIdx.x * 64;

    f32x4 acc[2][4];
#pragma unroll
    for (int i = 0; i < 2; ++i)
#pragma unroll
        for (int j = 0; j < 4; ++j) acc[i][j] = (f32x4){0.f, 0.f, 0.f, 0.f};

    for (int k0 = 0; k0 < K; k0 += 32) {
        bf16x8 af[2], bfr[4];
#pragma unroll
        for (int mi = 0; mi < 2; ++mi) {
            const int mb = m0 + mi * 16;
            if (mb >= M) { af[mi] = ZERO8; continue; }
            if (AF32) {
                const float* A = (const float*)Ap;
                float4 a0 = *(const float4*)(A + (size_t)(mb + lo) * K + k0 + quad * 8);
                float4 a1 = *(const float4*)(A + (size_t)(mb + lo) * K + k0 + quad * 8 + 4);
                bf16x8 f;
                f[0] = (short)f2bf(a0.x); f[1] = (short)f2bf(a0.y);
                f[2] = (short)f2bf(a0.z); f[3] = (short)f2bf(a0.w);
                f[4] = (short)f2bf(a1.x); f[5] = (short)f2bf(a1.y);
                f[6] = (short)f2bf(a1.z); f[7] = (short)f2bf(a1.w);
                af[mi] = f;
            } else {
                const unsigned short* A = (const unsigned short*)Ap;
                af[mi] = *(const bf16x8*)(A + (size_t)(mb + lo) * K + k0 + quad * 8);
            }
        }
#pragma unroll
        for (int ni = 0; ni < 4; ++ni)
            bfr[ni] = *(const bf16x8*)(W + (size_t)(n0 + ni * 16 + lo) * K + k0 + quad * 8);
#pragma unroll
        for (int mi = 0; mi < 2; ++mi)
#pragma unroll
            for (int ni = 0; ni < 4; ++ni)
                acc[mi][ni] = __builtin_amdgcn_mfma_f32_16x16x32_bf16(af[mi], bfr[ni], acc[mi][ni], 0, 0, 0);
    }

    float bn[4];
#pragma unroll
    for (int ni = 0; ni < 4; ++ni) {
        const int n = n0 + ni * 16 + lo;
        const float* bp = (n < bsplit) ? bias0 : bias1;
        const int bi = (n < bsplit) ? n : n - bsplit;
        bn[ni] = bp[bi];
    }
    if (SPLIT) {
        // stage fp8 tile in LDS, then cooperative wide stores
#pragma unroll
        for (int mi = 0; mi < 2; ++mi) {
#pragma unroll
            for (int ni = 0; ni < 4; ++ni) {
                const int n = ni * 16 + lo;
#pragma unroll
                for (int r = 0; r < 4; ++r) {
                    float o = acc[mi][ni][r] + bn[ni];
                    if (RELU) o = fmaxf(o, 0.f);
                    ctile[(wave * 32 + mi * 16 + quad * 4 + r) * 64 + n] = f2fp8(o);
                }
            }
        }
        __syncthreads();
        const int row = t >> 1, half = t & 1;
        const int grow = blockIdx.y * 128 + row;
        if (grow < M) {
            const unsigned char* srcp = &ctile[row * 64 + half * 32];
            unsigned char* dstp = Cf8 + (size_t)grow * 512 + n0 + half * 32;
            *(int4*)(dstp) = *(const int4*)(srcp);
            *(int4*)(dstp + 16) = *(const int4*)(srcp + 16);
        }
    } else {
#pragma unroll
        for (int mi = 0; mi < 2; ++mi) {
            const int mb = m0 + mi * 16;
            if (mb >= M) continue;
#pragma unroll
            for (int ni = 0; ni < 4; ++ni) {
                const int n = n0 + ni * 16 + lo;
#pragma unroll
                for (int r = 0; r < 4; ++r) {
                    float o = acc[mi][ni][r] + bn[ni];
                    if (RELU) o = fmaxf(o, 0.f);
                    Cbf[(size_t)(mb + quad * 4 + r) * N + n] = f2bf(o);
                }
            }
        }
    }
}

// ---------------- FiLM gemm: hbf = bf16((a@Wg^T+gb)*h + (a@Wb^T+bb)), in place ----
__global__ __launch_bounds__(256) void gemm_film_kernel(
    const unsigned short* __restrict__ A, const unsigned short* __restrict__ Wg,
    const unsigned short* __restrict__ Wb, const float* __restrict__ gb,
    const float* __restrict__ bb, unsigned short* __restrict__ hbf, int M) {
    const int K = 128, N = 128;
    const int t = threadIdx.x;
    const int wave = t >> 6, lane = t & 63;
    const int lo = lane & 15, quad = lane >> 4;
    const int m0 = blockIdx.y * 128 + wave * 32;
    const int n0 = blockIdx.x * 64;

    f32x4 accg[2][4], accb[2][4];
#pragma unroll
    for (int i = 0; i < 2; ++i)
#pragma unroll
        for (int j = 0; j < 4; ++j) { accg[i][j] = (f32x4){0.f,0.f,0.f,0.f}; accb[i][j] = accg[i][j]; }

    for (int k0 = 0; k0 < K; k0 += 32) {
        bf16x8 af[2], bg4[4];
#pragma unroll
        for (int mi = 0; mi < 2; ++mi) {
            const int mb = m0 + mi * 16;
            af[mi] = (mb < M) ? *(const bf16x8*)(A + (size_t)(mb + lo) * K + k0 + quad * 8)
                              : ZERO8;
        }
#pragma unroll
        for (int ni = 0; ni < 4; ++ni)
            bg4[ni] = *(const bf16x8*)(Wg + (size_t)(n0 + ni * 16 + lo) * K + k0 + quad * 8);
#pragma unroll
        for (int mi = 0; mi < 2; ++mi)
#pragma unroll
            for (int ni = 0; ni < 4; ++ni)
                accg[mi][ni] = __builtin_amdgcn_mfma_f32_16x16x32_bf16(af[mi], bg4[ni], accg[mi][ni], 0, 0, 0);
#pragma unroll
        for (int ni = 0; ni < 4; ++ni)
            bg4[ni] = *(const bf16x8*)(Wb + (size_t)(n0 + ni * 16 + lo) * K + k0 + quad * 8);
#pragma unroll
        for (int mi = 0; mi < 2; ++mi)
#pragma unroll
            for (int ni = 0; ni < 4; ++ni)
                accb[mi][ni] = __builtin_amdgcn_mfma_f32_16x16x32_bf16(af[mi], bg4[ni], accb[mi][ni], 0, 0, 0);
    }

#pragma unroll
    for (int mi = 0; mi < 2; ++mi) {
        const int mb = m0 + mi * 16;
        if (mb >= M) continue;
#pragma unroll
        for (int ni = 0; ni < 4; ++ni) {
            const int n = n0 + ni * 16 + lo;
            const float g = gb[n], b = bb[n];
#pragma unroll
            for (int r = 0; r < 4; ++r) {
                const size_t idx = (size_t)(mb + quad * 4 + r) * N + n;
                union { unsigned int i; float f; } hv; hv.i = (unsigned int)hbf[idx] << 16;
                hbf[idx] = f2bf((accg[mi][ni][r] + g) * hv.f + (accb[mi][ni][r] + b));
            }
        }
    }
}

// ---------------- q1 gemm + q2 head: atomicAdd(out, sum(relu(h@q1^T+b1)*q2w)) ----
__global__ __launch_bounds__(256) void gemm_q1_kernel(
    const unsigned short* __restrict__ A, const unsigned short* __restrict__ W,
    const float* __restrict__ q1b, const float* __restrict__ q2w,
    float* __restrict__ outsum, int M) {
    const int K = 128;
    const int t = threadIdx.x;
    const int wave = t >> 6, lane = t & 63;
    const int lo = lane & 15, quad = lane >> 4;
    const int m0 = blockIdx.y * 128 + wave * 32;
    const int n0 = blockIdx.x * 64;
    __shared__ float red[4];

    f32x4 acc[2][4];
#pragma unroll
    for (int i = 0; i < 2; ++i)
#pragma unroll
        for (int j = 0; j < 4; ++j) acc[i][j] = (f32x4){0.f, 0.f, 0.f, 0.f};

    for (int k0 = 0; k0 < K; k0 += 32) {
        bf16x8 af[2], bfr[4];
#pragma unroll
        for (int mi = 0; mi < 2; ++mi) {
            const int mb = m0 + mi * 16;
            af[mi] = (mb < M) ? *(const bf16x8*)(A + (size_t)(mb + lo) * K + k0 + quad * 8)
                              : ZERO8;
        }
#pragma unroll
        for (int ni = 0; ni < 4; ++ni)
            bfr[ni] = *(const bf16x8*)(W + (size_t)(n0 + ni * 16 + lo) * K + k0 + quad * 8);
#pragma unroll
        for (int mi = 0; mi < 2; ++mi)
#pragma unroll
            for (int ni = 0; ni < 4; ++ni)
                acc[mi][ni] = __builtin_amdgcn_mfma_f32_16x16x32_bf16(af[mi], bfr[ni], acc[mi][ni], 0, 0, 0);
    }

    float partial = 0.f;
#pragma unroll
    for (int mi = 0; mi < 2; ++mi) {
        const int mb = m0 + mi * 16;
        if (mb >= M) continue;
#pragma unroll
        for (int ni = 0; ni < 4; ++ni) {
            const int n = n0 + ni * 16 + lo;
            const float b = q1b[n], w = q2w[n];
#pragma unroll
            for (int r = 0; r < 4; ++r)
                partial += fmaxf(acc[mi][ni][r] + b, 0.f) * w;
        }
    }
    partial += __shfl_xor(partial, 1);  partial += __shfl_xor(partial, 2);
    partial += __shfl_xor(partial, 4);  partial += __shfl_xor(partial, 8);
    partial += __shfl_xor(partial, 16); partial += __shfl_xor(partial, 32);
    if (lane == 0) red[wave] = partial;
    __syncthreads();
    if (t == 0) atomicAdd(outsum, red[0] + red[1] + red[2] + red[3]);
}

// ---------------- fp32 vector GEMM (only for ap: K=16) -> bf16 out ----------------
template <int BK, bool RELU>
__global__ __launch_bounds__(256) void gemm_kernel(const float* __restrict__ A,
                                                   const float* __restrict__ W,
                                                   const float* __restrict__ bp,
                                                   unsigned short* __restrict__ Cbf,
                                                   int M, int N, int K) {
    __shared__ float As[BK][68];
    __shared__ float Ws[BK][68];
    const int t = threadIdx.x;
    const int m0 = blockIdx.y * 64;
    const int n0 = blockIdx.x * 64;
    const int tx = t & 15, ty = t >> 4;
    float acc[4][4];
#pragma unroll
    for (int i = 0; i < 4; ++i)
#pragma unroll
        for (int j = 0; j < 4; ++j) acc[i][j] = 0.f;

    for (int k0 = 0; k0 < K; k0 += BK) {
        const int r = t >> 2, cc = (t & 3) * 4;
        const int arow = m0 + r;
        float4 av = (arow < M) ? *(const float4*)(A + (size_t)arow * K + k0 + cc)
                               : make_float4(0.f, 0.f, 0.f, 0.f);
        As[cc + 0][r] = av.x; As[cc + 1][r] = av.y;
        As[cc + 2][r] = av.z; As[cc + 3][r] = av.w;
        float4 wv = *(const float4*)(W + (size_t)(n0 + r) * K + k0 + cc);
        Ws[cc + 0][r] = wv.x; Ws[cc + 1][r] = wv.y;
        Ws[cc + 2][r] = wv.z; Ws[cc + 3][r] = wv.w;
        __syncthreads();
#pragma unroll
        for (int k = 0; k < BK; ++k) {
            float4 a4 = *(const float4*)&As[k][ty * 4];
            float4 b4 = *(const float4*)&Ws[k][tx * 4];
            float a_[4] = {a4.x, a4.y, a4.z, a4.w};
            float b_[4] = {b4.x, b4.y, b4.z, b4.w};
#pragma unroll
            for (int i = 0; i < 4; ++i)
#pragma unroll
                for (int j = 0; j < 4; ++j) acc[i][j] += a_[i] * b_[j];
        }
        __syncthreads();
    }
    float4 bj = *(const float4*)(bp + n0 + tx * 4);
    float bb[4] = {bj.x, bj.y, bj.z, bj.w};
#pragma unroll
    for (int i = 0; i < 4; ++i) {
        int row = m0 + ty * 4 + i;
        if (row < M) {
            float o[4];
#pragma unroll
            for (int j = 0; j < 4; ++j) {
                o[j] = acc[i][j] + bb[j];
                if (RELU) o[j] = fmaxf(o[j], 0.f);
            }
            *(ushort4*)(Cbf + (size_t)row * N + n0 + tx * 4) =
                make_ushort4(f2bf(o[0]), f2bf(o[1]), f2bf(o[2]), f2bf(o[3]));
        }
    }
}

// ---------------- GAT K1: MFMA edge logits, LDS-staged wide fp8 gathers ----
// Wave = 16 CSR positions/batch; LDS slices are WAVE-PRIVATE -> no block
// barriers in the loop, only intra-wave lgkmcnt ordering.
#define LSTR 272
__global__ __launch_bounds__(256, 4) void gat_logit_kernel(
    const unsigned char* __restrict__ xf8,
    const int* __restrict__ csrs, const int* __restrict__ csrd,
    const unsigned short* __restrict__ eacsr, const unsigned short* __restrict__ we16,
    const float* __restrict__ att, float* __restrict__ logit, int E) {
    __shared__ float attl[256];
    __shared__ __align__(16) unsigned char xls[4][16 * LSTR];
    __shared__ __align__(16) unsigned char xrs[4][16 * LSTR];
    const int tid = threadIdx.x;
    attl[tid] = att[tid];
    const int wave = tid >> 6, lane = tid & 63;
    const int lo = lane & 15, quad = lane >> 4;
    const int sr_row = lane >> 2, c16 = (lane & 3) * 16;

    bf16x8 wef[16];
#pragma unroll
    for (int t = 0; t < 16; ++t)
        wef[t] = (quad < 2) ? *(const bf16x8*)(we16 + (size_t)(t * 16 + lo) * 16 + quad * 8)
                            : ZERO8;
    __syncthreads();   // attl visibility (one-time)

    const int nb = (E + 15) / 16;
    const int wstride = gridDim.x * 4;
    const int trips = (nb + wstride - 1) / wstride;
    for (int it = 0; it < trips; ++it) {
        const int b = blockIdx.x * 4 + wave + it * wstride;
        if (b >= nb) break;
        const int p0 = b * 16;
        {
            const int pr = min(p0 + sr_row, E - 1);
            const int sr = csrs[pr], dr = csrd[pr];
            const unsigned char* xs = xf8 + (size_t)sr * 512 + c16;
            const unsigned char* xrp = xf8 + (size_t)dr * 512 + 256 + c16;
            unsigned char* ld = &xls[wave][sr_row * LSTR + c16];
            unsigned char* rd = &xrs[wave][sr_row * LSTR + c16];
#pragma unroll
            for (int j = 0; j < 4; ++j) {
                *(int4*)(ld + j * 64) = *(const int4*)(xs + j * 64);
                *(int4*)(rd + j * 64) = *(const int4*)(xrp + j * 64);
            }
        }
        wave_lds_fence();   // writes visible to this wave's lanes
        {
            const bool valid = (p0 + lo) < E;
            const int p = valid ? (p0 + lo) : (E - 1);
            const bf16x8 eaf = (quad < 2)
                ? *(const bf16x8*)(eacsr + (size_t)p * 16 + quad * 8) : ZERO8;
            float ph0 = 0.f, ph1 = 0.f;
#pragma unroll
            for (int t = 0; t < 16; ++t) {
                f32x4 D = __builtin_amdgcn_mfma_f32_16x16x32_bf16(
                    wef[t], eaf, (f32x4){0.f, 0.f, 0.f, 0.f}, 0, 0, 0);
                const int c0 = t * 16 + quad * 4;
                const unsigned int xlu = *(const unsigned int*)&xls[wave][lo * LSTR + c0];
                const unsigned int xru = *(const unsigned int*)&xrs[wave][lo * LSTR + c0];
                const f32x2 l01 = __builtin_amdgcn_cvt_pk_f32_fp8(xlu, false);
                const f32x2 l23 = __builtin_amdgcn_cvt_pk_f32_fp8(xlu, true);
                const f32x2 r01 = __builtin_amdgcn_cvt_pk_f32_fp8(xru, false);
                const f32x2 r23 = __builtin_amdgcn_cvt_pk_f32_fp8(xru, true);
                const float4 at4 = *(const float4*)&attl[c0];
                float vx = l01.x + r01.x + D[0];
                float vy = l01.y + r01.y + D[1];
                float vz = l23.x + r23.x + D[2];
                float vw = l23.y + r23.y + D[3];
                vx = fmaxf(vx, 0.2f * vx); vy = fmaxf(vy, 0.2f * vy);
                vz = fmaxf(vz, 0.2f * vz); vw = fmaxf(vw, 0.2f * vw);
                const float pt = vx * at4.x + vy * at4.y + vz * at4.z + vw * at4.w;
                if (t < 8) ph0 += pt; else ph1 += pt;
            }
            ph0 += __shfl_xor(ph0, 16); ph0 += __shfl_xor(ph0, 32);
            ph1 += __shfl_xor(ph1, 16); ph1 += __shfl_xor(ph1, 32);
            if (valid) {
                if (quad == 0) logit[p0 + lo] = ph0;
                else if (quad == 1) logit[(size_t)E + p0 + lo] = ph1;
            }
        }
        wave_lds_fence();   // reads done before next trip's writes
    }
}

// ---------------- GAT K2: per-node softmax + weighted gather-sum (fp8) ----
__global__ __launch_bounds__(256) void gat_na_kernel(
    const unsigned char* __restrict__ xf8,
    const int* __restrict__ rowp, const int* __restrict__ csrs,
    const float* __restrict__ wgt, const float* __restrict__ bias,
    unsigned short* __restrict__ houtb, int nnodes, int E) {
    const int lane = threadIdx.x & 63;
    const int node = blockIdx.x * 4 + (threadIdx.x >> 6);
    if (node >= nnodes) return;
    const int rs = rowp[node], re = rowp[node + 1];
    const int h = lane >> 5, l = lane & 31;
    const float* lg = wgt + (size_t)h * E;

    float mx = -INFINITY;
    for (int i = rs + l; i < re; i += 32) mx = fmaxf(mx, lg[i]);
    mx = fmaxf(mx, __shfl_xor(mx, 1));  mx = fmaxf(mx, __shfl_xor(mx, 2));
    mx = fmaxf(mx, __shfl_xor(mx, 4));  mx = fmaxf(mx, __shfl_xor(mx, 8));
    mx = fmaxf(mx, __shfl_xor(mx, 16));
    float sum = 0.f;
    for (int i = rs + l; i < re; i += 32) sum += __expf(lg[i] - mx);
    sum += __shfl_xor(sum, 1);  sum += __shfl_xor(sum, 2);  sum += __shfl_xor(sum, 4);
    sum += __shfl_xor(sum, 8);  sum += __shfl_xor(sum, 16);
    const float inv = (re > rs) ? 1.f / sum : 0.f;

    float4 acc0 = make_float4(0.f, 0.f, 0.f, 0.f), acc1 = acc0;
    int i = rs;
    for (; i + 1 < re; i += 2) {
        const int s0 = csrs[i], s1 = csrs[i + 1];
        const float w0 = __expf(lg[i] - mx) * inv;
        const float w1 = __expf(lg[i + 1] - mx) * inv;
        const unsigned int u0 = *(const unsigned int*)(xf8 + (size_t)s0 * 512 + 4 * lane);
        const unsigned int u1 = *(const unsigned int*)(xf8 + (size_t)s1 * 512 + 4 * lane);
        const f32x2 a01 = __builtin_amdgcn_cvt_pk_f32_fp8(u0, false);
        const f32x2 a23 = __builtin_amdgcn_cvt_pk_f32_fp8(u0, true);
        const f32x2 b01 = __builtin_amdgcn_cvt_pk_f32_fp8(u1, false);
        const f32x2 b23 = __builtin_amdgcn_cvt_pk_f32_fp8(u1, true);
        acc0.x += w0 * a01.x; acc0.y += w0 * a01.y; acc0.z += w0 * a23.x; acc0.w += w0 * a23.y;
        acc1.x += w1 * b01.x; acc1.y += w1 * b01.y; acc1.z += w1 * b23.x; acc1.w += w1 * b23.y;
    }
    if (i < re) {
        const int s0 = csrs[i];
        const float w0 = __expf(lg[i] - mx) * inv;
        const unsigned int u0 = *(const unsigned int*)(xf8 + (size_t)s0 * 512 + 4 * lane);
        const f32x2 a01 = __builtin_amdgcn_cvt_pk_f32_fp8(u0, false);
        const f32x2 a23 = __builtin_amdgcn_cvt_pk_f32_fp8(u0, true);
        acc0.x += w0 * a01.x; acc0.y += w0 * a01.y; acc0.z += w0 * a23.x; acc0.w += w0 * a23.y;
    }
    float ox = acc0.x + acc1.x, oy = acc0.y + acc1.y;
    float oz = acc0.z + acc1.z, ow = acc0.w + acc1.w;
    ox += __shfl_xor(ox, 32); oy += __shfl_xor(oy, 32);
    oz += __shfl_xor(oz, 32); ow += __shfl_xor(ow, 32);
    if (lane < 32) {
        float4 bu = *(const float4*)(bias + 4 * lane);
        *(ushort4*)(houtb + (size_t)node * 128 + 4 * lane) = make_ushort4(
            f2bf(fmaxf(0.5f * ox + bu.x, 0.f)), f2bf(fmaxf(0.5f * oy + bu.y, 0.f)),
            f2bf(fmaxf(0.5f * oz + bu.z, 0.f)), f2bf(fmaxf(0.5f * ow + bu.w, 0.f)));
    }
}

// ---------------- out = sum/N + q2_b ----------------
__global__ void final_kernel(const float* __restrict__ s, const float* __restrict__ q2b,
                             float* __restrict__ out, float invn) {
    out[0] = s[0] * invn + q2b[0];
}

extern "C" void kernel_launch(void* const* d_in, const int* in_sizes, int n_in,
                              void* d_out, int out_size, void* d_ws, size_t ws_size,
                              hipStream_t stream) {
    const int N = in_sizes[0] / 128;   // 20000
    const int E = in_sizes[1] / 2;     // 320000

    typedef const float* fp;
    fp x      = (fp)d_in[0];
    const int* ei = (const int*)d_in[1];
    fp ea     = (fp)d_in[2];
    fp action = (fp)d_in[3];
    fp inp_W  = (fp)d_in[4];
    fp inp_b  = (fp)d_in[5];
    fp ap_W = (fp)d_in[27], ap_b = (fp)d_in[28];
    fp g_W  = (fp)d_in[29], g_b  = (fp)d_in[30];
    fp be_W = (fp)d_in[31], be_b = (fp)d_in[32];
    fp q1_W = (fp)d_in[33], q1_b = (fp)d_in[34];
    fp q2_W = (fp)d_in[35], q2_b = (fp)d_in[36];

    char* base = (char*)d_ws;
    size_t off = 0;
    auto alloc = [&](size_t bytes) { char* p = base + off; off = (off + bytes + 255) & ~(size_t)255; return p; };
    unsigned char*  xf8 = (unsigned char*)alloc((size_t)N * 512);       // xl|xr fp8
    float* col  = (float*)alloc(128 * 4);
    int* deg    = (int*)alloc((size_t)N * 4);
    int* rowp   = (int*)alloc((size_t)(N + 1) * 4);
    int* cur    = (int*)alloc((size_t)N * 4);
    int* csrs   = (int*)alloc((size_t)E * 4);
    int* csrd   = (int*)alloc((size_t)E * 4);
    unsigned short* eacsr = (unsigned short*)alloc((size_t)E * 16 * 2); // ea bf16 CSR order
    float* wgt  = (float*)alloc((size_t)2 * E * 4);                     // logits
    unsigned short* hbf = (unsigned short*)alloc((size_t)N * 128 * 2);
    unsigned short* wbf = (unsigned short*)alloc((262144 + 3 * 4096) * 2);
    unsigned short* abf = (unsigned short*)wgt;  // a bf16 [N,128]: wgt dead at FiLM stage
    (void)ws_size; (void)n_in; (void)out_size;

    unsigned short* winp = wbf;            // 128x128
    unsigned short* w1l  = wbf + 16384;    // [512,128] fused pairs
    unsigned short* w1r  = w1l + 32768;
    unsigned short* w2l  = w1r + 32768;
    unsigned short* w2r  = w2l + 32768;
    unsigned short* wal  = w2r + 32768;
    unsigned short* war  = wal + 32768;
    unsigned short* wg   = war + 32768;    // 128x128
    unsigned short* wbe  = wg + 16384;
    unsigned short* wq1  = wbe + 16384;
    unsigned short* wep1 = wq1 + 16384;    // 3x [256,16] bf16 We (unpadded)
    unsigned short* wep2 = wep1 + 4096;
    unsigned short* wep3 = wep2 + 4096;

    const int* src = ei;
    const int* dst = ei + E;

    CvtDescs cd;
    int ce = 0;
    auto addc = [&](const float* s, unsigned short* d, int n) { cd.src[ce] = s; cd.dst[ce] = d; cd.n4[ce] = n / 4; ++ce; };
    addc(inp_W, winp, 16384);
    addc((fp)d_in[6],  w1l, 32768); addc((fp)d_in[8],  w1r, 32768);
    addc((fp)d_in[13], w2l, 32768); addc((fp)d_in[15], w2r, 32768);
    addc((fp)d_in[20], wal, 32768); addc((fp)d_in[22], war, 32768);
    addc(g_W, wg, 16384); addc(be_W, wbe, 16384); addc(q1_W, wq1, 16384);
    addc((fp)d_in[10], wep1, 4096); addc((fp)d_in[17], wep2, 4096); addc((fp)d_in[24], wep3, 4096);
    cd.cnt = ce;
    cvt_many_kernel<<<1024, 256, 0, stream>>>(cd);

    hipMemsetAsync(deg, 0, (size_t)N * 4, stream);
    hist_kernel<<<(E + 255) / 256, 256, 0, stream>>>(dst, deg, E);
    scan_kernel<<<1, 1024, 0, stream>>>(deg, rowp, cur, N);
    scatter_kernel<<<(E + 255) / 256, 256, 0, stream>>>(src, dst, cur, (const float4*)ea,
                                                        csrs, csrd, (ushort4*)eacsr, E);

    const int my = (N + 127) / 128;
    const int nodeg = (N + 3) / 4;

    auto run_gat = [&](const unsigned short* wep, const float* at, const float* bi,
                       unsigned short* hb) {
        gat_logit_kernel<<<2500, 256, 0, stream>>>(xf8, csrs, csrd, eacsr, wep, at, wgt, E);
        gat_na_kernel<<<nodeg, 256, 0, stream>>>(xf8, rowp, csrs, wgt, bi, hb, N, E);
    };

    // h0 = relu(x @ inp_W^T + inp_b) -> bf16 (x read as fp32, cvt in-kernel)
    gemm_mfma_kernel<true, false, true><<<dim3(2, my), 256, 0, stream>>>(
        x, winp, inp_b, inp_b, 128, hbf, nullptr, N, 128, 128);

    // s1
    gemm_mfma_kernel<false, true, false><<<dim3(8, my), 256, 0, stream>>>(
        hbf, w1l, (fp)d_in[7], (fp)d_in[9], 256, nullptr, xf8, N, 512, 128);
    run_gat(wep1, (fp)d_in[11], (fp)d_in[12], hbf);
    // s2
    gemm_mfma_kernel<false, true, false><<<dim3(8, my), 256, 0, stream>>>(
        hbf, w2l, (fp)d_in[14], (fp)d_in[16], 256, nullptr, xf8, N, 512, 128);
    run_gat(wep2, (fp)d_in[18], (fp)d_in[19], hbf);

    // FiLM: a = relu(action@ap^T+ap_b) -> abf; fused gamma/beta gemm in-place on hbf
    gemm_kernel<16, true><<<dim3(2, (N + 63) / 64), 256, 0, stream>>>(
        action, ap_W, ap_b, abf, N, 128, 16);
    gemm_film_kernel<<<dim3(2, my), 256, 0, stream>>>(abf, wg, wbe, g_b, be_b, hbf, N);

    // sa
    gemm_mfma_kernel<false, true, false><<<dim3(8, my), 256, 0, stream>>>(
        hbf, wal, (fp)d_in[21], (fp)d_in[23], 256, nullptr, xf8, N, 512, 128);
    run_gat(wep3, (fp)d_in[25], (fp)d_in[26], hbf);

    // q1 + q2 + mean fused
    hipMemsetAsync(col, 0, 4, stream);
    gemm_q1_kernel<<<dim3(2, my), 256, 0, stream>>>(hbf, wq1, q1_b, q2_W, col, N);
    final_kernel<<<1, 1, 0, stream>>>(col, q2_b, (float*)d_out, 1.0f / (float)N);
}

// Round 13
// 449.018 us; speedup vs baseline: 2.3843x; 1.0245x over previous
//
#include <hip/hip_runtime.h>
#include <hip/hip_bf16.h>

// EdgeAwareCritic: 3x GATv2 (H=2 heads, HID=128) + FiLM + MLP head, scalar output.
// fp32 inputs; GEMMs in bf16 MFMA. GAT per layer:
//   K1: edge-parallel MFMA logits; xl/xr fp8 via LDS-staged wide loads
//       (wave-private slices -> wave-level waits, no block barriers).
//   K2: per-node softmax (exp-no-max, clamp 60 — logits ~±0.1) + weighted
//       aggregate (fp8 gathers, f32 accum).
// NOTE (R9 lesson): global f32 atomics as edge-accumulators cause ~300 MB HBM
// write amplification on 8-XCD MI355X — never again.
// NOTE (R12 lesson): abf must have a DEDICATED allocation (2.56 MB wgt alias
// overflowed into hbf -> silent corruption that nearly passed).

typedef __attribute__((ext_vector_type(8))) short bf16x8;   // 8 bf16 = 4 VGPR
typedef __attribute__((ext_vector_type(4))) float f32x4;
typedef __attribute__((ext_vector_type(2))) float f32x2;

#define ZERO8 ((bf16x8){0, 0, 0, 0, 0, 0, 0, 0})

__device__ __forceinline__ unsigned short f2bf(float f) {
    union { float f; unsigned int i; } v; v.f = f;
    unsigned int x = v.i;
    x += 0x7fffu + ((x >> 16) & 1u);   // round-to-nearest-even
    return (unsigned short)(x >> 16);
}
__device__ __forceinline__ unsigned char f2fp8(float f) {
    return (unsigned char)(__builtin_amdgcn_cvt_pk_fp8_f32(f, f, 0, false) & 0xFF);
}
__device__ __forceinline__ void wave_lds_fence() {
    // LDS slices are wave-private: order ds_write -> ds_read within the wave.
    __builtin_amdgcn_wave_barrier();
    asm volatile("s_waitcnt lgkmcnt(0)" ::: "memory");
    __builtin_amdgcn_wave_barrier();
}

// ---------------- multi-tensor fp32 -> bf16 convert (RNE) ----------------
#define MAXCVT 16
struct CvtDescs {
    const float* src[MAXCVT];
    unsigned short* dst[MAXCVT];
    int n4[MAXCVT];
    int cnt;
};
__global__ __launch_bounds__(256) void cvt_many_kernel(CvtDescs d) {
    const int tid = blockIdx.x * blockDim.x + threadIdx.x;
    const int stride = gridDim.x * blockDim.x;
    for (int e = 0; e < d.cnt; ++e) {
        const float4* s = (const float4*)d.src[e];
        ushort4* o = (ushort4*)d.dst[e];
        const int n = d.n4[e];
        for (int i = tid; i < n; i += stride) {
            float4 v = s[i];
            o[i] = make_ushort4(f2bf(v.x), f2bf(v.y), f2bf(v.z), f2bf(v.w));
        }
    }
}

// ---------------- CSR build ----------------
__global__ void hist_kernel(const int* __restrict__ dst, int* __restrict__ deg, int n) {
    int i = blockIdx.x * blockDim.x + threadIdx.x;
    if (i < n) atomicAdd(&deg[dst[i]], 1);
}

__global__ __launch_bounds__(1024) void scan_kernel(const int* __restrict__ deg,
                                                    int* __restrict__ rowp,
                                                    int* __restrict__ cur, int n) {
    __shared__ int sums[1024];
    const int t = threadIdx.x;
    const int PER = 20;
    int base = t * PER;
    int local[PER];
    int run = 0;
#pragma unroll
    for (int i = 0; i < PER; ++i) {
        int v = (base + i < n) ? deg[base + i] : 0;
        local[i] = run; run += v;
    }
    sums[t] = run; __syncthreads();
    for (int off = 1; off < 1024; off <<= 1) {
        int v = (t >= off) ? sums[t - off] : 0;
        __syncthreads();
        sums[t] += v;
        __syncthreads();
    }
    int offs = (t > 0) ? sums[t - 1] : 0;
#pragma unroll
    for (int i = 0; i < PER; ++i) {
        int idx = base + i;
        if (idx < n) { int v = offs + local[i]; rowp[idx] = v; cur[idx] = v; }
    }
    if (t == 0) rowp[n] = sums[1023];
}

// scatter: CSR src/dst lists + edge_attr rows -> CSR order bf16 (unpadded, 32 B)
__global__ void scatter_kernel(const int* __restrict__ src, const int* __restrict__ dst,
                               int* __restrict__ cur, const float4* __restrict__ ea,
                               int* __restrict__ csrs, int* __restrict__ csrd,
                               ushort4* __restrict__ eacsr, int n) {
    int i = blockIdx.x * blockDim.x + threadIdx.x;
    if (i < n) {
        int d = dst[i];
        int p = atomicAdd(&cur[d], 1);
        csrs[p] = src[i];
        csrd[p] = d;
        const float4* er = ea + (size_t)i * 4;
        ushort4* eo = eacsr + (size_t)p * 4;
#pragma unroll
        for (int q = 0; q < 4; ++q) {
            float4 v = er[q];
            eo[q] = make_ushort4(f2bf(v.x), f2bf(v.y), f2bf(v.z), f2bf(v.w));
        }
    }
}

// ---------------- bf16 MFMA GEMM: C = A@W^T + bias ----
// SPLIT=false: Cbf[M,N] bf16. SPLIT=true (N=512): Cf8[M,512] fp8 via LDS-staged
// wide stores. AF32: A is fp32, converted in-kernel.
template <bool RELU, bool SPLIT, bool AF32>
__global__ __launch_bounds__(256) void gemm_mfma_kernel(
    const void* __restrict__ Ap, const unsigned short* __restrict__ W,
    const float* __restrict__ bias0, const float* __restrict__ bias1, int bsplit,
    unsigned short* __restrict__ Cbf, unsigned char* __restrict__ Cf8,
    int M, int N, int K) {
    __shared__ unsigned char ctile[SPLIT ? 128 * 64 : 64];
    const int t = threadIdx.x;
    const int wave = t >> 6, lane = t & 63;
    const int lo = lane & 15, quad = lane >> 4;
    const int m0 = blockIdx.y * 128 + wave * 32;
    const int n0 = blockIdx.x * 64;

    f32x4 acc[2][4];
#pragma unroll
    for (int i = 0; i < 2; ++i)
#pragma unroll
        for (int j = 0; j < 4; ++j) acc[i][j] = (f32x4){0.f, 0.f, 0.f, 0.f};

    for (int k0 = 0; k0 < K; k0 += 32) {
        bf16x8 af[2], bfr[4];
#pragma unroll
        for (int mi = 0; mi < 2; ++mi) {
            const int mb = m0 + mi * 16;
            if (mb >= M) { af[mi] = ZERO8; continue; }
            if (AF32) {
                const float* A = (const float*)Ap;
                float4 a0 = *(const float4*)(A + (size_t)(mb + lo) * K + k0 + quad * 8);
                float4 a1 = *(const float4*)(A + (size_t)(mb + lo) * K + k0 + quad * 8 + 4);
                bf16x8 f;
                f[0] = (short)f2bf(a0.x); f[1] = (short)f2bf(a0.y);
                f[2] = (short)f2bf(a0.z); f[3] = (short)f2bf(a0.w);
                f[4] = (short)f2bf(a1.x); f[5] = (short)f2bf(a1.y);
                f[6] = (short)f2bf(a1.z); f[7] = (short)f2bf(a1.w);
                af[mi] = f;
            } else {
                const unsigned short* A = (const unsigned short*)Ap;
                af[mi] = *(const bf16x8*)(A + (size_t)(mb + lo) * K + k0 + quad * 8);
            }
        }
#pragma unroll
        for (int ni = 0; ni < 4; ++ni)
            bfr[ni] = *(const bf16x8*)(W + (size_t)(n0 + ni * 16 + lo) * K + k0 + quad * 8);
#pragma unroll
        for (int mi = 0; mi < 2; ++mi)
#pragma unroll
            for (int ni = 0; ni < 4; ++ni)
                acc[mi][ni] = __builtin_amdgcn_mfma_f32_16x16x32_bf16(af[mi], bfr[ni], acc[mi][ni], 0, 0, 0);
    }

    float bn[4];
#pragma unroll
    for (int ni = 0; ni < 4; ++ni) {
        const int n = n0 + ni * 16 + lo;
        const float* bp = (n < bsplit) ? bias0 : bias1;
        const int bi = (n < bsplit) ? n : n - bsplit;
        bn[ni] = bp[bi];
    }
    if (SPLIT) {
        // stage fp8 tile in LDS, then cooperative wide stores
#pragma unroll
        for (int mi = 0; mi < 2; ++mi) {
#pragma unroll
            for (int ni = 0; ni < 4; ++ni) {
                const int n = ni * 16 + lo;
#pragma unroll
                for (int r = 0; r < 4; ++r) {
                    float o = acc[mi][ni][r] + bn[ni];
                    if (RELU) o = fmaxf(o, 0.f);
                    ctile[(wave * 32 + mi * 16 + quad * 4 + r) * 64 + n] = f2fp8(o);
                }
            }
        }
        __syncthreads();
        const int row = t >> 1, half = t & 1;
        const int grow = blockIdx.y * 128 + row;
        if (grow < M) {
            const unsigned char* srcp = &ctile[row * 64 + half * 32];
            unsigned char* dstp = Cf8 + (size_t)grow * 512 + n0 + half * 32;
            *(int4*)(dstp) = *(const int4*)(srcp);
            *(int4*)(dstp + 16) = *(const int4*)(srcp + 16);
        }
    } else {
#pragma unroll
        for (int mi = 0; mi < 2; ++mi) {
            const int mb = m0 + mi * 16;
            if (mb >= M) continue;
#pragma unroll
            for (int ni = 0; ni < 4; ++ni) {
                const int n = n0 + ni * 16 + lo;
#pragma unroll
                for (int r = 0; r < 4; ++r) {
                    float o = acc[mi][ni][r] + bn[ni];
                    if (RELU) o = fmaxf(o, 0.f);
                    Cbf[(size_t)(mb + quad * 4 + r) * N + n] = f2bf(o);
                }
            }
        }
    }
}

// ---------------- FiLM gemm: hbf = bf16((a@Wg^T+gb)*h + (a@Wb^T+bb)), in place ----
__global__ __launch_bounds__(256) void gemm_film_kernel(
    const unsigned short* __restrict__ A, const unsigned short* __restrict__ Wg,
    const unsigned short* __restrict__ Wb, const float* __restrict__ gb,
    const float* __restrict__ bb, unsigned short* __restrict__ hbf, int M) {
    const int K = 128, N = 128;
    const int t = threadIdx.x;
    const int wave = t >> 6, lane = t & 63;
    const int lo = lane & 15, quad = lane >> 4;
    const int m0 = blockIdx.y * 128 + wave * 32;
    const int n0 = blockIdx.x * 64;

    f32x4 accg[2][4], accb[2][4];
#pragma unroll
    for (int i = 0; i < 2; ++i)
#pragma unroll
        for (int j = 0; j < 4; ++j) { accg[i][j] = (f32x4){0.f,0.f,0.f,0.f}; accb[i][j] = accg[i][j]; }

    for (int k0 = 0; k0 < 128; k0 += 32) {
        bf16x8 af[2], bg4[4];
#pragma unroll
        for (int mi = 0; mi < 2; ++mi) {
            const int mb = m0 + mi * 16;
            af[mi] = (mb < M) ? *(const bf16x8*)(A + (size_t)(mb + lo) * K + k0 + quad * 8)
                              : ZERO8;
        }
#pragma unroll
        for (int ni = 0; ni < 4; ++ni)
            bg4[ni] = *(const bf16x8*)(Wg + (size_t)(n0 + ni * 16 + lo) * K + k0 + quad * 8);
#pragma unroll
        for (int mi = 0; mi < 2; ++mi)
#pragma unroll
            for (int ni = 0; ni < 4; ++ni)
                accg[mi][ni] = __builtin_amdgcn_mfma_f32_16x16x32_bf16(af[mi], bg4[ni], accg[mi][ni], 0, 0, 0);
#pragma unroll
        for (int ni = 0; ni < 4; ++ni)
            bg4[ni] = *(const bf16x8*)(Wb + (size_t)(n0 + ni * 16 + lo) * K + k0 + quad * 8);
#pragma unroll
        for (int mi = 0; mi < 2; ++mi)
#pragma unroll
            for (int ni = 0; ni < 4; ++ni)
                accb[mi][ni] = __builtin_amdgcn_mfma_f32_16x16x32_bf16(af[mi], bg4[ni], accb[mi][ni], 0, 0, 0);
    }

#pragma unroll
    for (int mi = 0; mi < 2; ++mi) {
        const int mb = m0 + mi * 16;
        if (mb >= M) continue;
#pragma unroll
        for (int ni = 0; ni < 4; ++ni) {
            const int n = n0 + ni * 16 + lo;
            const float g = gb[n], b = bb[n];
#pragma unroll
            for (int r = 0; r < 4; ++r) {
                const size_t idx = (size_t)(mb + quad * 4 + r) * N + n;
                union { unsigned int i; float f; } hv; hv.i = (unsigned int)hbf[idx] << 16;
                hbf[idx] = f2bf((accg[mi][ni][r] + g) * hv.f + (accb[mi][ni][r] + b));
            }
        }
    }
}

// ---------------- q1 gemm + q2 head: atomicAdd(out, sum(relu(h@q1^T+b1)*q2w)) ----
__global__ __launch_bounds__(256) void gemm_q1_kernel(
    const unsigned short* __restrict__ A, const unsigned short* __restrict__ W,
    const float* __restrict__ q1b, const float* __restrict__ q2w,
    float* __restrict__ outsum, int M) {
    const int K = 128;
    const int t = threadIdx.x;
    const int wave = t >> 6, lane = t & 63;
    const int lo = lane & 15, quad = lane >> 4;
    const int m0 = blockIdx.y * 128 + wave * 32;
    const int n0 = blockIdx.x * 64;
    __shared__ float red[4];

    f32x4 acc[2][4];
#pragma unroll
    for (int i = 0; i < 2; ++i)
#pragma unroll
        for (int j = 0; j < 4; ++j) acc[i][j] = (f32x4){0.f, 0.f, 0.f, 0.f};

    for (int k0 = 0; k0 < K; k0 += 32) {
        bf16x8 af[2], bfr[4];
#pragma unroll
        for (int mi = 0; mi < 2; ++mi) {
            const int mb = m0 + mi * 16;
            af[mi] = (mb < M) ? *(const bf16x8*)(A + (size_t)(mb + lo) * K + k0 + quad * 8)
                              : ZERO8;
        }
#pragma unroll
        for (int ni = 0; ni < 4; ++ni)
            bfr[ni] = *(const bf16x8*)(W + (size_t)(n0 + ni * 16 + lo) * K + k0 + quad * 8);
#pragma unroll
        for (int mi = 0; mi < 2; ++mi)
#pragma unroll
            for (int ni = 0; ni < 4; ++ni)
                acc[mi][ni] = __builtin_amdgcn_mfma_f32_16x16x32_bf16(af[mi], bfr[ni], acc[mi][ni], 0, 0, 0);
    }

    float partial = 0.f;
#pragma unroll
    for (int mi = 0; mi < 2; ++mi) {
        const int mb = m0 + mi * 16;
        if (mb >= M) continue;
#pragma unroll
        for (int ni = 0; ni < 4; ++ni) {
            const int n = n0 + ni * 16 + lo;
            const float b = q1b[n], w = q2w[n];
#pragma unroll
            for (int r = 0; r < 4; ++r)
                partial += fmaxf(acc[mi][ni][r] + b, 0.f) * w;
        }
    }
    partial += __shfl_xor(partial, 1);  partial += __shfl_xor(partial, 2);
    partial += __shfl_xor(partial, 4);  partial += __shfl_xor(partial, 8);
    partial += __shfl_xor(partial, 16); partial += __shfl_xor(partial, 32);
    if (lane == 0) red[wave] = partial;
    __syncthreads();
    if (t == 0) atomicAdd(outsum, red[0] + red[1] + red[2] + red[3]);
}

// ---------------- fp32 vector GEMM (only for ap: K=16) -> bf16 out ----------------
template <int BK, bool RELU>
__global__ __launch_bounds__(256) void gemm_kernel(const float* __restrict__ A,
                                                   const float* __restrict__ W,
                                                   const float* __restrict__ bp,
                                                   unsigned short* __restrict__ Cbf,
                                                   int M, int N, int K) {
    __shared__ float As[BK][68];
    __shared__ float Ws[BK][68];
    const int t = threadIdx.x;
    const int m0 = blockIdx.y * 64;
    const int n0 = blockIdx.x * 64;
    const int tx = t & 15, ty = t >> 4;
    float acc[4][4];
#pragma unroll
    for (int i = 0; i < 4; ++i)
#pragma unroll
        for (int j = 0; j < 4; ++j) acc[i][j] = 0.f;

    for (int k0 = 0; k0 < K; k0 += BK) {
        const int r = t >> 2, cc = (t & 3) * 4;
        const int arow = m0 + r;
        float4 av = (arow < M) ? *(const float4*)(A + (size_t)arow * K + k0 + cc)
                               : make_float4(0.f, 0.f, 0.f, 0.f);
        As[cc + 0][r] = av.x; As[cc + 1][r] = av.y;
        As[cc + 2][r] = av.z; As[cc + 3][r] = av.w;
        float4 wv = *(const float4*)(W + (size_t)(n0 + r) * K + k0 + cc);
        Ws[cc + 0][r] = wv.x; Ws[cc + 1][r] = wv.y;
        Ws[cc + 2][r] = wv.z; Ws[cc + 3][r] = wv.w;
        __syncthreads();
#pragma unroll
        for (int k = 0; k < BK; ++k) {
            float4 a4 = *(const float4*)&As[k][ty * 4];
            float4 b4 = *(const float4*)&Ws[k][tx * 4];
            float a_[4] = {a4.x, a4.y, a4.z, a4.w};
            float b_[4] = {b4.x, b4.y, b4.z, b4.w};
#pragma unroll
            for (int i = 0; i < 4; ++i)
#pragma unroll
                for (int j = 0; j < 4; ++j) acc[i][j] += a_[i] * b_[j];
        }
        __syncthreads();
    }
    float4 bj = *(const float4*)(bp + n0 + tx * 4);
    float bb[4] = {bj.x, bj.y, bj.z, bj.w};
#pragma unroll
    for (int i = 0; i < 4; ++i) {
        int row = m0 + ty * 4 + i;
        if (row < M) {
            float o[4];
#pragma unroll
            for (int j = 0; j < 4; ++j) {
                o[j] = acc[i][j] + bb[j];
                if (RELU) o[j] = fmaxf(o[j], 0.f);
            }
            *(ushort4*)(Cbf + (size_t)row * N + n0 + tx * 4) =
                make_ushort4(f2bf(o[0]), f2bf(o[1]), f2bf(o[2]), f2bf(o[3]));
        }
    }
}

// ---------------- GAT K1: MFMA edge logits, LDS-staged wide fp8 gathers ----
// Wave = 16 CSR positions/batch; LDS slices are WAVE-PRIVATE -> no block
// barriers in the loop, only intra-wave lgkmcnt ordering.
#define LSTR 272
__global__ __launch_bounds__(256, 4) void gat_logit_kernel(
    const unsigned char* __restrict__ xf8,
    const int* __restrict__ csrs, const int* __restrict__ csrd,
    const unsigned short* __restrict__ eacsr, const unsigned short* __restrict__ we16,
    const float* __restrict__ att, float* __restrict__ logit, int E) {
    __shared__ float attl[256];
    __shared__ __align__(16) unsigned char xls[4][16 * LSTR];
    __shared__ __align__(16) unsigned char xrs[4][16 * LSTR];
    const int tid = threadIdx.x;
    attl[tid] = att[tid];
    const int wave = tid >> 6, lane = tid & 63;
    const int lo = lane & 15, quad = lane >> 4;
    const int sr_row = lane >> 2, c16 = (lane & 3) * 16;

    bf16x8 wef[16];
#pragma unroll
    for (int t = 0; t < 16; ++t)
        wef[t] = (quad < 2) ? *(const bf16x8*)(we16 + (size_t)(t * 16 + lo) * 16 + quad * 8)
                            : ZERO8;
    __syncthreads();   // attl visibility (one-time)

    const int nb = (E + 15) / 16;
    const int wstride = gridDim.x * 4;
    const int trips = (nb + wstride - 1) / wstride;
    for (int it = 0; it < trips; ++it) {
        const int b = blockIdx.x * 4 + wave + it * wstride;
        if (b >= nb) break;
        const int p0 = b * 16;
        {
            const int pr = min(p0 + sr_row, E - 1);
            const int sr = csrs[pr], dr = csrd[pr];
            const unsigned char* xs = xf8 + (size_t)sr * 512 + c16;
            const unsigned char* xrp = xf8 + (size_t)dr * 512 + 256 + c16;
            unsigned char* ld = &xls[wave][sr_row * LSTR + c16];
            unsigned char* rd = &xrs[wave][sr_row * LSTR + c16];
#pragma unroll
            for (int j = 0; j < 4; ++j) {
                *(int4*)(ld + j * 64) = *(const int4*)(xs + j * 64);
                *(int4*)(rd + j * 64) = *(const int4*)(xrp + j * 64);
            }
        }
        wave_lds_fence();   // writes visible to this wave's lanes
        {
            const bool valid = (p0 + lo) < E;
            const int p = valid ? (p0 + lo) : (E - 1);
            const bf16x8 eaf = (quad < 2)
                ? *(const bf16x8*)(eacsr + (size_t)p * 16 + quad * 8) : ZERO8;
            float ph0 = 0.f, ph1 = 0.f;
#pragma unroll
            for (int t = 0; t < 16; ++t) {
                f32x4 D = __builtin_amdgcn_mfma_f32_16x16x32_bf16(
                    wef[t], eaf, (f32x4){0.f, 0.f, 0.f, 0.f}, 0, 0, 0);
                const int c0 = t * 16 + quad * 4;
                const unsigned int xlu = *(const unsigned int*)&xls[wave][lo * LSTR + c0];
                const unsigned int xru = *(const unsigned int*)&xrs[wave][lo * LSTR + c0];
                const f32x2 l01 = __builtin_amdgcn_cvt_pk_f32_fp8(xlu, false);
                const f32x2 l23 = __builtin_amdgcn_cvt_pk_f32_fp8(xlu, true);
                const f32x2 r01 = __builtin_amdgcn_cvt_pk_f32_fp8(xru, false);
                const f32x2 r23 = __builtin_amdgcn_cvt_pk_f32_fp8(xru, true);
                const float4 at4 = *(const float4*)&attl[c0];
                float vx = l01.x + r01.x + D[0];
                float vy = l01.y + r01.y + D[1];
                float vz = l23.x + r23.x + D[2];
                float vw = l23.y + r23.y + D[3];
                vx = fmaxf(vx, 0.2f * vx); vy = fmaxf(vy, 0.2f * vy);
                vz = fmaxf(vz, 0.2f * vz); vw = fmaxf(vw, 0.2f * vw);
                const float pt = vx * at4.x + vy * at4.y + vz * at4.z + vw * at4.w;
                if (t < 8) ph0 += pt; else ph1 += pt;
            }
            ph0 += __shfl_xor(ph0, 16); ph0 += __shfl_xor(ph0, 32);
            ph1 += __shfl_xor(ph1, 16); ph1 += __shfl_xor(ph1, 32);
            if (valid) {
                if (quad == 0) logit[p0 + lo] = ph0;
                else if (quad == 1) logit[(size_t)E + p0 + lo] = ph1;
            }
        }
        wave_lds_fence();   // reads done before next trip's writes
    }
}

// ---------------- GAT K2: per-node softmax + weighted gather-sum (fp8) ----
// exp without max-subtraction (logits ~±0.1; clamp 60 guards overflow) —
// numerically identical in the softmax ratio, removes one pass over logits.
__global__ __launch_bounds__(256) void gat_na_kernel(
    const unsigned char* __restrict__ xf8,
    const int* __restrict__ rowp, const int* __restrict__ csrs,
    const float* __restrict__ wgt, const float* __restrict__ bias,
    unsigned short* __restrict__ houtb, int nnodes, int E) {
    const int lane = threadIdx.x & 63;
    const int node = blockIdx.x * 4 + (threadIdx.x >> 6);
    if (node >= nnodes) return;
    const int rs = rowp[node], re = rowp[node + 1];
    const int h = lane >> 5, l = lane & 31;
    const float* lg = wgt + (size_t)h * E;

    float sum = 0.f;
    for (int i = rs + l; i < re; i += 32) sum += __expf(fminf(lg[i], 60.f));
    sum += __shfl_xor(sum, 1);  sum += __shfl_xor(sum, 2);  sum += __shfl_xor(sum, 4);
    sum += __shfl_xor(sum, 8);  sum += __shfl_xor(sum, 16);
    const float inv = (re > rs) ? 1.f / sum : 0.f;

    float4 acc0 = make_float4(0.f, 0.f, 0.f, 0.f), acc1 = acc0;
    int i = rs;
    for (; i + 1 < re; i += 2) {
        const int s0 = csrs[i], s1 = csrs[i + 1];
        const float w0 = __expf(fminf(lg[i], 60.f)) * inv;
        const float w1 = __expf(fminf(lg[i + 1], 60.f)) * inv;
        const unsigned int u0 = *(const unsigned int*)(xf8 + (size_t)s0 * 512 + 4 * lane);
        const unsigned int u1 = *(const unsigned int*)(xf8 + (size_t)s1 * 512 + 4 * lane);
        const f32x2 a01 = __builtin_amdgcn_cvt_pk_f32_fp8(u0, false);
        const f32x2 a23 = __builtin_amdgcn_cvt_pk_f32_fp8(u0, true);
        const f32x2 b01 = __builtin_amdgcn_cvt_pk_f32_fp8(u1, false);
        const f32x2 b23 = __builtin_amdgcn_cvt_pk_f32_fp8(u1, true);
        acc0.x += w0 * a01.x; acc0.y += w0 * a01.y; acc0.z += w0 * a23.x; acc0.w += w0 * a23.y;
        acc1.x += w1 * b01.x; acc1.y += w1 * b01.y; acc1.z += w1 * b23.x; acc1.w += w1 * b23.y;
    }
    if (i < re) {
        const int s0 = csrs[i];
        const float w0 = __expf(fminf(lg[i], 60.f)) * inv;
        const unsigned int u0 = *(const unsigned int*)(xf8 + (size_t)s0 * 512 + 4 * lane);
        const f32x2 a01 = __builtin_amdgcn_cvt_pk_f32_fp8(u0, false);
        const f32x2 a23 = __builtin_amdgcn_cvt_pk_f32_fp8(u0, true);
        acc0.x += w0 * a01.x; acc0.y += w0 * a01.y; acc0.z += w0 * a23.x; acc0.w += w0 * a23.y;
    }
    float ox = acc0.x + acc1.x, oy = acc0.y + acc1.y;
    float oz = acc0.z + acc1.z, ow = acc0.w + acc1.w;
    // mean over heads: lane l (head0) pairs with lane l^32 (head1, same channels)
    ox += __shfl_xor(ox, 32); oy += __shfl_xor(oy, 32);
    oz += __shfl_xor(oz, 32); ow += __shfl_xor(ow, 32);
    if (lane < 32) {
        float4 bu = *(const float4*)(bias + 4 * lane);
        *(ushort4*)(houtb + (size_t)node * 128 + 4 * lane) = make_ushort4(
            f2bf(fmaxf(0.5f * ox + bu.x, 0.f)), f2bf(fmaxf(0.5f * oy + bu.y, 0.f)),
            f2bf(fmaxf(0.5f * oz + bu.z, 0.f)), f2bf(fmaxf(0.5f * ow + bu.w, 0.f)));
    }
}

// ---------------- out = sum/N + q2_b ----------------
__global__ void final_kernel(const float* __restrict__ s, const float* __restrict__ q2b,
                             float* __restrict__ out, float invn) {
    out[0] = s[0] * invn + q2b[0];
}

extern "C" void kernel_launch(void* const* d_in, const int* in_sizes, int n_in,
                              void* d_out, int out_size, void* d_ws, size_t ws_size,
                              hipStream_t stream) {
    const int N = in_sizes[0] / 128;   // 20000
    const int E = in_sizes[1] / 2;     // 320000

    typedef const float* fp;
    fp x      = (fp)d_in[0];
    const int* ei = (const int*)d_in[1];
    fp ea     = (fp)d_in[2];
    fp action = (fp)d_in[3];
    fp inp_W  = (fp)d_in[4];
    fp inp_b  = (fp)d_in[5];
    fp ap_W = (fp)d_in[27], ap_b = (fp)d_in[28];
    fp g_W  = (fp)d_in[29], g_b  = (fp)d_in[30];
    fp be_W = (fp)d_in[31], be_b = (fp)d_in[32];
    fp q1_W = (fp)d_in[33], q1_b = (fp)d_in[34];
    fp q2_W = (fp)d_in[35], q2_b = (fp)d_in[36];

    char* base = (char*)d_ws;
    size_t off = 0;
    auto alloc = [&](size_t bytes) { char* p = base + off; off = (off + bytes + 255) & ~(size_t)255; return p; };
    unsigned char*  xf8 = (unsigned char*)alloc((size_t)N * 512);       // xl|xr fp8
    float* col  = (float*)alloc(128 * 4);
    int* deg    = (int*)alloc((size_t)N * 4);
    int* rowp   = (int*)alloc((size_t)(N + 1) * 4);
    int* cur    = (int*)alloc((size_t)N * 4);
    int* csrs   = (int*)alloc((size_t)E * 4);
    int* csrd   = (int*)alloc((size_t)E * 4);
    unsigned short* eacsr = (unsigned short*)alloc((size_t)E * 16 * 2); // ea bf16 CSR order
    float* wgt  = (float*)alloc((size_t)2 * E * 4);                     // logits
    unsigned short* hbf = (unsigned short*)alloc((size_t)N * 128 * 2);
    unsigned short* abf = (unsigned short*)alloc((size_t)N * 128 * 2);  // DEDICATED (R12 bug)
    unsigned short* wbf = (unsigned short*)alloc((262144 + 3 * 4096) * 2);
    (void)ws_size; (void)n_in; (void)out_size;

    unsigned short* winp = wbf;            // 128x128
    unsigned short* w1l  = wbf + 16384;    // [512,128] fused pairs
    unsigned short* w1r  = w1l + 32768;
    unsigned short* w2l  = w1r + 32768;
    unsigned short* w2r  = w2l + 32768;
    unsigned short* wal  = w2r + 32768;
    unsigned short* war  = wal + 32768;
    unsigned short* wg   = war + 32768;    // 128x128
    unsigned short* wbe  = wg + 16384;
    unsigned short* wq1  = wbe + 16384;
    unsigned short* wep1 = wq1 + 16384;    // 3x [256,16] bf16 We (unpadded)
    unsigned short* wep2 = wep1 + 4096;
    unsigned short* wep3 = wep2 + 4096;

    const int* src = ei;
    const int* dst = ei + E;

    CvtDescs cd;
    int ce = 0;
    auto addc = [&](const float* s, unsigned short* d, int n) { cd.src[ce] = s; cd.dst[ce] = d; cd.n4[ce] = n / 4; ++ce; };
    addc(inp_W, winp, 16384);
    addc((fp)d_in[6],  w1l, 32768); addc((fp)d_in[8],  w1r, 32768);
    addc((fp)d_in[13], w2l, 32768); addc((fp)d_in[15], w2r, 32768);
    addc((fp)d_in[20], wal, 32768); addc((fp)d_in[22], war, 32768);
    addc(g_W, wg, 16384); addc(be_W, wbe, 16384); addc(q1_W, wq1, 16384);
    addc((fp)d_in[10], wep1, 4096); addc((fp)d_in[17], wep2, 4096); addc((fp)d_in[24], wep3, 4096);
    cd.cnt = ce;
    cvt_many_kernel<<<1024, 256, 0, stream>>>(cd);

    hipMemsetAsync(deg, 0, (size_t)N * 4, stream);
    hist_kernel<<<(E + 255) / 256, 256, 0, stream>>>(dst, deg, E);
    scan_kernel<<<1, 1024, 0, stream>>>(deg, rowp, cur, N);
    scatter_kernel<<<(E + 255) / 256, 256, 0, stream>>>(src, dst, cur, (const float4*)ea,
                                                        csrs, csrd, (ushort4*)eacsr, E);

    const int my = (N + 127) / 128;
    const int nodeg = (N + 3) / 4;

    auto run_gat = [&](const unsigned short* wep, const float* at, const float* bi,
                       unsigned short* hb) {
        gat_logit_kernel<<<2500, 256, 0, stream>>>(xf8, csrs, csrd, eacsr, wep, at, wgt, E);
        gat_na_kernel<<<nodeg, 256, 0, stream>>>(xf8, rowp, csrs, wgt, bi, hb, N, E);
    };

    // h0 = relu(x @ inp_W^T + inp_b) -> bf16 (x read as fp32, cvt in-kernel)
    gemm_mfma_kernel<true, false, true><<<dim3(2, my), 256, 0, stream>>>(
        x, winp, inp_b, inp_b, 128, hbf, nullptr, N, 128, 128);

    // s1
    gemm_mfma_kernel<false, true, false><<<dim3(8, my), 256, 0, stream>>>(
        hbf, w1l, (fp)d_in[7], (fp)d_in[9], 256, nullptr, xf8, N, 512, 128);
    run_gat(wep1, (fp)d_in[11], (fp)d_in[12], hbf);
    // s2
    gemm_mfma_kernel<false, true, false><<<dim3(8, my), 256, 0, stream>>>(
        hbf, w2l, (fp)d_in[14], (fp)d_in[16], 256, nullptr, xf8, N, 512, 128);
    run_gat(wep2, (fp)d_in[18], (fp)d_in[19], hbf);

    // FiLM: a = relu(action@ap^T+ap_b) -> abf (dedicated); gamma/beta gemm in-place on hbf
    gemm_kernel<16, true><<<dim3(2, (N + 63) / 64), 256, 0, stream>>>(
        action, ap_W, ap_b, abf, N, 128, 16);
    gemm_film_kernel<<<dim3(2, my), 256, 0, stream>>>(abf, wg, wbe, g_b, be_b, hbf, N);

    // sa
    gemm_mfma_kernel<false, true, false><<<dim3(8, my), 256, 0, stream>>>(
        hbf, wal, (fp)d_in[21], (fp)d_in[23], 256, nullptr, xf8, N, 512, 128);
    run_gat(wep3, (fp)d_in[25], (fp)d_in[26], hbf);

    // q1 + q2 + mean fused
    hipMemsetAsync(col, 0, 4, stream);
    gemm_q1_kernel<<<dim3(2, my), 256, 0, stream>>>(hbf, wq1, q1_b, q2_W, col, N);
    final_kernel<<<1, 1, 0, stream>>>(col, q2_b, (float*)d_out, 1.0f / (float)N);
}